// Round 3
// baseline (1760.698 us; speedup 1.0000x reference)
//
#include <hip/hip_runtime.h>

#define NN 100000
#define FIN 256
#define HD 128
#define CD 64

// ---------- bf16 helpers ----------
__device__ __forceinline__ float bf2f(unsigned int u16) {
    union { unsigned int u; float f; } v;
    v.u = (u16 & 0xffffu) << 16;
    return v.f;
}
__device__ __forceinline__ unsigned short f2bf(float f) {
    union { float f; unsigned int u; } v;
    v.f = f;
    unsigned int u = v.u + 0x7fffu + ((v.u >> 16) & 1u);  // RNE
    return (unsigned short)(u >> 16);
}
__device__ __forceinline__ float4 fma4(float s, float4 a, float4 acc) {
    acc.x += s * a.x; acc.y += s * a.y; acc.z += s * a.z; acc.w += s * a.w;
    return acc;
}

// ---------- dtype detection: are the float inputs bf16 or fp32? ----------
// Look at even-indexed 16-bit halves of x. If x is bf16 N(0,1), exponent field
// is in [112,134] essentially always. If x is fp32, even halves are the LOW
// 16 bits (little-endian) = random mantissa bits -> ~9% in range.
__global__ void k_detect(const unsigned short* __restrict__ x, int* __restrict__ flag) {
    __shared__ int s[256];
    int t = threadIdx.x;
    int c = 0;
    for (int i = t; i < 16384; i += 256) {
        unsigned int e = (x[2 * i] >> 7) & 0xFF;
        c += (e >= 112 && e <= 134) ? 1 : 0;
    }
    s[t] = c;
    __syncthreads();
    for (int off = 128; off > 0; off >>= 1) {
        if (t < off) s[t] += s[t + off];
        __syncthreads();
    }
    if (t == 0) *flag = (s[0] > 8192) ? 1 : 0;  // 1 = inputs are bf16
}

// convert (or copy) a weight matrix into bf16 scratch
__global__ void k_conv1(const void* __restrict__ src, unsigned short* __restrict__ dst,
                        int n, const int* __restrict__ dflag) {
    int i = blockIdx.x * 256 + threadIdx.x;
    if (i >= n) return;
    if (*dflag) dst[i] = ((const unsigned short*)src)[i];
    else        dst[i] = f2bf(((const float*)src)[i]);
}

// ---------- preprocessing: degree histogram, scan, counting sort ----------
__global__ void k_hist(const int* __restrict__ row, int* __restrict__ cnt, int E) {
    int e = blockIdx.x * 256 + threadIdx.x;
    if (e < E) {
        unsigned int r = (unsigned int)row[e];
        if (r >= NN) r = 0;  // defensive clamp
        atomicAdd(&cnt[r], 1);
    }
}

__global__ void k_scan_a(const int* __restrict__ cnt, int* __restrict__ bsum, int n) {
    __shared__ int s[256];
    int i = blockIdx.x * 256 + threadIdx.x;
    s[threadIdx.x] = (i < n) ? cnt[i] : 0;
    __syncthreads();
    for (int off = 128; off > 0; off >>= 1) {
        if (threadIdx.x < off) s[threadIdx.x] += s[threadIdx.x + off];
        __syncthreads();
    }
    if (threadIdx.x == 0) bsum[blockIdx.x] = s[0];
}

__global__ void k_scan_b(int* bsum, int nchunks) {
    __shared__ int s[512];
    int t = threadIdx.x;
    int v = (t < nchunks) ? bsum[t] : 0;
    s[t] = v;
    __syncthreads();
    for (int off = 1; off < 512; off <<= 1) {
        int x = (t >= off) ? s[t - off] : 0;
        __syncthreads();
        s[t] += x;
        __syncthreads();
    }
    if (t < nchunks) bsum[t] = s[t] - v;  // exclusive
}

__global__ void k_scan_c(const int* __restrict__ cnt, const int* __restrict__ bsum,
                         int* __restrict__ offs, int* __restrict__ cursor, int n) {
    __shared__ int s[256];
    int t = threadIdx.x;
    int i = blockIdx.x * 256 + t;
    int v = (i < n) ? cnt[i] : 0;
    s[t] = v;
    __syncthreads();
    for (int off = 1; off < 256; off <<= 1) {
        int x = (t >= off) ? s[t - off] : 0;
        __syncthreads();
        s[t] += x;
        __syncthreads();
    }
    if (i < n) {
        int ex = bsum[blockIdx.x] + s[t] - v;
        offs[i] = ex;
        cursor[i] = ex;
    }
}

__global__ void k_scatter(const int* __restrict__ row, const int* __restrict__ col,
                          int* __restrict__ cursor, int* __restrict__ colS, int E) {
    int e = blockIdx.x * 256 + threadIdx.x;
    if (e < E) {
        unsigned int r = (unsigned int)row[e];
        if (r >= NN) r = 0;
        unsigned int c = (unsigned int)col[e];
        if (c >= NN) c = 0;
        int p = atomicAdd(&cursor[r], 1);
        colS[p] = (int)c;
    }
}

__global__ void k_dinv(const int* __restrict__ cnt, float* __restrict__ dinv, int n) {
    int i = blockIdx.x * 256 + threadIdx.x;
    if (i < n) dinv[i] = rsqrtf((float)(cnt[i] + 1));  // +1 self loop
}

// ---------- GEMM: G[r][c] = dinv[r] * sum_k relu?(A[r][k]) * W[k][c]; W,G bf16 ----------
// AMODE 0: A is bf16.  AMODE 2: A dtype chosen at runtime via dflag (layer 0).
template <int K, int COLS, bool RELU, int AMODE>
__global__ __launch_bounds__(256) void k_gemm(const void* __restrict__ Av,
                                              const unsigned short* __restrict__ W,
                                              const float* __restrict__ dinv,
                                              unsigned short* __restrict__ G, int nrows,
                                              const int* __restrict__ dflag) {
    constexpr int CG = COLS / 4;          // col groups
    constexpr int RPB = (256 / CG) * 4;   // rows per block: 32 (COLS=128) or 64 (COLS=64)
    int t = threadIdx.x;
    int c0 = (t % CG) * 4;
    int r0 = blockIdx.x * RPB + (t / CG) * 4;

    const unsigned short* Ab = (const unsigned short*)Av;
    const float* Af = (const float*)Av;
    bool abf = true;
    if constexpr (AMODE == 2) abf = (*dflag != 0);

    float4 acc[4];
    acc[0] = acc[1] = acc[2] = acc[3] = make_float4(0.f, 0.f, 0.f, 0.f);

    for (int k0 = 0; k0 < K; k0 += 4) {
        float4 a[4];
#pragma unroll
        for (int i = 0; i < 4; i++) {
            int r = r0 + i;
            if (r < nrows) {
                float4 av;
                bool use_bf = (AMODE == 0) || abf;
                if (use_bf) {
                    uint2 u = *(const uint2*)(Ab + (size_t)r * K + k0);
                    av = make_float4(bf2f(u.x), bf2f(u.x >> 16), bf2f(u.y), bf2f(u.y >> 16));
                } else {
                    av = *(const float4*)(Af + (size_t)r * K + k0);
                }
                if constexpr (RELU) {
                    av.x = fmaxf(av.x, 0.f); av.y = fmaxf(av.y, 0.f);
                    av.z = fmaxf(av.z, 0.f); av.w = fmaxf(av.w, 0.f);
                }
                a[i] = av;
            } else {
                a[i] = make_float4(0.f, 0.f, 0.f, 0.f);
            }
        }
        float4 wv[4];
#pragma unroll
        for (int j = 0; j < 4; j++) {
            uint2 u = *(const uint2*)(W + (size_t)(k0 + j) * COLS + c0);
            wv[j] = make_float4(bf2f(u.x), bf2f(u.x >> 16), bf2f(u.y), bf2f(u.y >> 16));
        }
#pragma unroll
        for (int i = 0; i < 4; i++) {
            acc[i] = fma4(a[i].x, wv[0], acc[i]);
            acc[i] = fma4(a[i].y, wv[1], acc[i]);
            acc[i] = fma4(a[i].z, wv[2], acc[i]);
            acc[i] = fma4(a[i].w, wv[3], acc[i]);
        }
    }
#pragma unroll
    for (int i = 0; i < 4; i++) {
        int r = r0 + i;
        if (r >= nrows) continue;
        float s = dinv[r];
        unsigned int lo = (unsigned int)f2bf(acc[i].x * s) | ((unsigned int)f2bf(acc[i].y * s) << 16);
        unsigned int hi = (unsigned int)f2bf(acc[i].z * s) | ((unsigned int)f2bf(acc[i].w * s) << 16);
        *(uint2*)(G + (size_t)r * COLS + c0) = make_uint2(lo, hi);
    }
}

// ---------- aggregate: out[r] = relu?(dinv[r]*(g[r] + sum_{c in adj(r)} g[c])) ----------
// Always writes bf16 to obf. If FINAL, additionally writes to oraw with dtype per dflag.
template <int D, bool RELU, bool FINAL>
__global__ __launch_bounds__(256) void k_agg(const unsigned short* __restrict__ g,
                                             const int* __restrict__ colS,
                                             const int* __restrict__ offs,
                                             const int* __restrict__ cnt,
                                             const float* __restrict__ dinv,
                                             unsigned short* __restrict__ obf,
                                             void* __restrict__ oraw,
                                             const int* __restrict__ dflag, int n) {
    int lane = threadIdx.x & 63;
    int node = blockIdx.x * 4 + (threadIdx.x >> 6);
    if (node >= n) return;
    int start = offs[node];
    int deg = cnt[node];

    float a0 = 0.f, a1 = 0.f;
    if constexpr (D == 128) {
        unsigned int u = *(const unsigned int*)(g + (size_t)node * 128 + lane * 2);
        a0 = bf2f(u); a1 = bf2f(u >> 16);
    } else {
        a0 = bf2f(g[(size_t)node * 64 + lane]);
    }

    for (int base = 0; base < deg; base += 64) {
        int rem = deg - base;
        int nb = rem < 64 ? rem : 64;
        int cidx = 0;
        if (lane < nb) cidx = colS[start + base + lane];
        int j = 0;
        for (; j + 4 <= nb; j += 4) {
            int c0 = __shfl(cidx, j);
            int c1 = __shfl(cidx, j + 1);
            int c2 = __shfl(cidx, j + 2);
            int c3 = __shfl(cidx, j + 3);
            if constexpr (D == 128) {
                unsigned int u0 = *(const unsigned int*)(g + (size_t)c0 * 128 + lane * 2);
                unsigned int u1 = *(const unsigned int*)(g + (size_t)c1 * 128 + lane * 2);
                unsigned int u2 = *(const unsigned int*)(g + (size_t)c2 * 128 + lane * 2);
                unsigned int u3 = *(const unsigned int*)(g + (size_t)c3 * 128 + lane * 2);
                a0 += bf2f(u0); a1 += bf2f(u0 >> 16);
                a0 += bf2f(u1); a1 += bf2f(u1 >> 16);
                a0 += bf2f(u2); a1 += bf2f(u2 >> 16);
                a0 += bf2f(u3); a1 += bf2f(u3 >> 16);
            } else {
                unsigned short u0 = g[(size_t)c0 * 64 + lane];
                unsigned short u1 = g[(size_t)c1 * 64 + lane];
                unsigned short u2 = g[(size_t)c2 * 64 + lane];
                unsigned short u3 = g[(size_t)c3 * 64 + lane];
                a0 += bf2f(u0) + bf2f(u1) + bf2f(u2) + bf2f(u3);
            }
        }
        for (; j < nb; j++) {
            int cj = __shfl(cidx, j);
            if constexpr (D == 128) {
                unsigned int u = *(const unsigned int*)(g + (size_t)cj * 128 + lane * 2);
                a0 += bf2f(u); a1 += bf2f(u >> 16);
            } else {
                a0 += bf2f(g[(size_t)cj * 64 + lane]);
            }
        }
    }

    float s = dinv[node];
    a0 *= s; a1 *= s;
    if constexpr (RELU) { a0 = fmaxf(a0, 0.f); a1 = fmaxf(a1, 0.f); }

    if constexpr (D == 128) {
        *(unsigned int*)(obf + (size_t)node * 128 + lane * 2) =
            (unsigned int)f2bf(a0) | ((unsigned int)f2bf(a1) << 16);
    } else {
        obf[(size_t)node * 64 + lane] = f2bf(a0);
        if constexpr (FINAL) {
            if (*dflag) ((unsigned short*)oraw)[(size_t)node * 64 + lane] = f2bf(a0);
            else        ((float*)oraw)[(size_t)node * 64 + lane] = a0;
        }
    }
}

// ---------- correlation metric (bf16 input) ----------
template <int D>
__global__ void k_colsum(const unsigned short* __restrict__ in, float* __restrict__ colsum, int n) {
    int t = threadIdx.x;
    int c = t % D;
    constexpr int RPB = 256 / D;
    int r = blockIdx.x * RPB + t / D;
    int stride = gridDim.x * RPB;
    float s = 0.f;
    for (; r < n; r += stride) s += bf2f(in[(size_t)r * D + c]);
    atomicAdd(&colsum[c], s);
}

template <int D>
__global__ __launch_bounds__(256) void k_cov(const unsigned short* __restrict__ in,
                                             const float* __restrict__ colsum,
                                             float* __restrict__ cov, int n) {
    constexpr int TI = D / 16;  // 8 for D=128, 4 for D=64
    __shared__ float rb[16][D];
    __shared__ float smean[D];
    int t = threadIdx.x;
    if (t < D) smean[t] = colsum[t] * (1.0f / (float)NN);
    __syncthreads();

    float acc[TI * TI];
#pragma unroll
    for (int q = 0; q < TI * TI; q++) acc[q] = 0.f;
    int i0 = (t >> 4) * TI;
    int j0 = (t & 15) * TI;

    for (int base = blockIdx.x * 16; base < n; base += gridDim.x * 16) {
        for (int idx = t; idx < 16 * D; idx += 256) {
            int r = idx / D, c = idx % D;
            rb[r][c] = bf2f(in[(size_t)(base + r) * D + c]) - smean[c];
        }
        __syncthreads();
#pragma unroll
        for (int r = 0; r < 16; r++) {
            float ai[TI], aj[TI];
#pragma unroll
            for (int q = 0; q < TI; q += 4) {
                *(float4*)&ai[q] = *(const float4*)&rb[r][i0 + q];
                *(float4*)&aj[q] = *(const float4*)&rb[r][j0 + q];
            }
#pragma unroll
            for (int ii = 0; ii < TI; ii++)
#pragma unroll
                for (int jj = 0; jj < TI; jj++) acc[ii * TI + jj] += ai[ii] * aj[jj];
        }
        __syncthreads();
    }
#pragma unroll
    for (int ii = 0; ii < TI; ii++)
#pragma unroll
        for (int jj = 0; jj < TI; jj++)
            atomicAdd(&cov[(i0 + ii) * D + (j0 + jj)], acc[ii * TI + jj]);
}

template <int D>
__global__ __launch_bounds__(256) void k_fin(const float* __restrict__ cov,
                                             void* __restrict__ out, long long idx,
                                             const int* __restrict__ dflag) {
    __shared__ float sd[D];
    __shared__ float red[256];
    int t = threadIdx.x;
    if (t < D) sd[t] = sqrtf(fmaxf(cov[t * D + t], 1e-12f));
    __syncthreads();
    float s = 0.f;
    for (int i2 = t; i2 < D * D; i2 += 256) {
        int i = i2 / D, j = i2 % D;
        if (j > i) s += fabsf(cov[i2] / (sd[i] * sd[j]));
    }
    red[t] = s;
    __syncthreads();
    for (int off = 128; off > 0; off >>= 1) {
        if (t < off) red[t] += red[t + off];
        __syncthreads();
    }
    if (t == 0) {
        float v = red[0] / (float)(D * (D - 1) / 2);
        if (*dflag) ((unsigned short*)out)[idx] = f2bf(v);
        else        ((float*)out)[idx] = v;
    }
}

// ---------- launch ----------
extern "C" void kernel_launch(void* const* d_in, const int* in_sizes, int n_in,
                              void* d_out, int out_size, void* d_ws, size_t ws_size,
                              hipStream_t stream) {
    const void* x = d_in[0];
    const int* ei = (const int*)d_in[1];

    int E = in_sizes[1] / 2;
    const int* row = ei;
    const int* col = ei + E;

    // workspace carve (256B aligned), total ~59.5 MB
    char* w = (char*)d_ws;
    auto carve = [&](size_t bytes) {
        void* p = (void*)w;
        w += (bytes + 255) & ~(size_t)255;
        return p;
    };
    int* cnt = (int*)carve((size_t)NN * 4);
    int* offs = (int*)carve((size_t)NN * 4);
    int* cursor = (int*)carve((size_t)NN * 4);
    int* bsum = (int*)carve(512 * 4);
    int* colS = (int*)carve((size_t)E * 4);
    float* dinv = (float*)carve((size_t)NN * 4);
    float* colsum = (float*)carve(HD * 4);
    float* covs = (float*)carve(HD * HD * 4);
    int* dflag = (int*)carve(256);
    unsigned short* wc = (unsigned short*)carve((size_t)(FIN * HD + HD * HD * 2 + HD * CD) * 2);
    unsigned short* bufA = (unsigned short*)carve((size_t)NN * HD * 2);
    unsigned short* bufB = (unsigned short*)carve((size_t)NN * HD * 2);

    unsigned short* wc0 = wc;                       // 256x128
    unsigned short* wc1 = wc + FIN * HD;            // 128x128
    unsigned short* wc2 = wc1 + HD * HD;            // 128x128
    unsigned short* wc3 = wc2 + HD * HD;            // 128x64

    int nchunks = (NN + 255) / 256;  // 391
    int eblocks = (E + 255) / 256;

    // dtype detection + weight conversion
    k_detect<<<1, 256, 0, stream>>>((const unsigned short*)x, dflag);
    k_conv1<<<(FIN * HD + 255) / 256, 256, 0, stream>>>(d_in[2], wc0, FIN * HD, dflag);
    k_conv1<<<(HD * HD + 255) / 256, 256, 0, stream>>>(d_in[3], wc1, HD * HD, dflag);
    k_conv1<<<(HD * HD + 255) / 256, 256, 0, stream>>>(d_in[4], wc2, HD * HD, dflag);
    k_conv1<<<(HD * CD + 255) / 256, 256, 0, stream>>>(d_in[5], wc3, HD * CD, dflag);

    // preprocessing
    hipMemsetAsync(cnt, 0, (size_t)NN * 4, stream);
    k_hist<<<eblocks, 256, 0, stream>>>(row, cnt, E);
    k_scan_a<<<nchunks, 256, 0, stream>>>(cnt, bsum, NN);
    k_scan_b<<<1, 512, 0, stream>>>(bsum, nchunks);
    k_scan_c<<<nchunks, 256, 0, stream>>>(cnt, bsum, offs, cursor, NN);
    k_scatter<<<eblocks, 256, 0, stream>>>(row, col, cursor, colS, E);
    k_dinv<<<nchunks, 256, 0, stream>>>(cnt, dinv, NN);

    // layer 0: x @ W0 -> B ; aggregate -> A (relu)
    k_gemm<256, 128, false, 2><<<NN / 32, 256, 0, stream>>>(x, wc0, dinv, bufB, NN, dflag);
    k_agg<128, true, false><<<NN / 4, 256, 0, stream>>>(bufB, colS, offs, cnt, dinv, bufA, nullptr, dflag, NN);
    // layer 1
    k_gemm<128, 128, false, 0><<<NN / 32, 256, 0, stream>>>(bufA, wc1, dinv, bufB, NN, dflag);
    k_agg<128, true, false><<<NN / 4, 256, 0, stream>>>(bufB, colS, offs, cnt, dinv, bufA, nullptr, dflag, NN);
    // layer 2 (output kept pre-ReLU in bufA for corr_2)
    k_gemm<128, 128, false, 0><<<NN / 32, 256, 0, stream>>>(bufA, wc2, dinv, bufB, NN, dflag);
    k_agg<128, false, false><<<NN / 4, 256, 0, stream>>>(bufB, colS, offs, cnt, dinv, bufA, nullptr, dflag, NN);

    // corr_2 on bufA (bf16, D=128)
    hipMemsetAsync(colsum, 0, HD * 4, stream);
    hipMemsetAsync(covs, 0, HD * HD * 4, stream);
    k_colsum<128><<<128, 256, 0, stream>>>(bufA, colsum, NN);
    k_cov<128><<<256, 256, 0, stream>>>(bufA, colsum, covs, NN);
    k_fin<128><<<1, 256, 0, stream>>>(covs, d_out, (long long)NN * CD, dflag);

    // layer 3: relu(bufA) @ W3 -> B ; aggregate -> d_out (+ bf16 mirror in bufA)
    k_gemm<128, 64, true, 0><<<(NN + 63) / 64, 256, 0, stream>>>(bufA, wc3, dinv, bufB, NN, dflag);
    k_agg<64, false, true><<<NN / 4, 256, 0, stream>>>(bufB, colS, offs, cnt, dinv, bufA, d_out, dflag, NN);

    // corr on final output (bf16 mirror in bufA, D=64)
    hipMemsetAsync(colsum, 0, HD * 4, stream);
    hipMemsetAsync(covs, 0, HD * HD * 4, stream);
    k_colsum<64><<<128, 256, 0, stream>>>(bufA, colsum, NN);
    k_cov<64><<<256, 256, 0, stream>>>(bufA, colsum, covs, NN);
    k_fin<64><<<1, 256, 0, stream>>>(covs, d_out, (long long)NN * CD + 1, dflag);
}

// Round 4
// 1255.814 us; speedup vs baseline: 1.4020x; 1.4020x over previous
//
#include <hip/hip_runtime.h>

#define NN 100000
#define FIN 256
#define HD 128
#define CD 64

typedef __attribute__((ext_vector_type(8))) short bf16x8;
typedef __attribute__((ext_vector_type(4))) float f32x4;

// ---------- bf16 helpers ----------
__device__ __forceinline__ float bf2f(unsigned int u16) {
    union { unsigned int u; float f; } v;
    v.u = (u16 & 0xffffu) << 16;
    return v.f;
}
__device__ __forceinline__ unsigned short f2bf(float f) {
    union { float f; unsigned int u; } v;
    v.f = f;
    unsigned int u = v.u + 0x7fffu + ((v.u >> 16) & 1u);  // RNE
    return (unsigned short)(u >> 16);
}

// ---------- dtype detection (inputs bf16 vs fp32; R3 measured: fp32) ----------
__global__ void k_detect(const unsigned short* __restrict__ x, int* __restrict__ flag) {
    __shared__ int s[256];
    int t = threadIdx.x;
    int c = 0;
    for (int i = t; i < 16384; i += 256) {
        unsigned int e = (x[2 * i] >> 7) & 0xFF;
        c += (e >= 112 && e <= 134) ? 1 : 0;
    }
    s[t] = c;
    __syncthreads();
    for (int off = 128; off > 0; off >>= 1) {
        if (t < off) s[t] += s[t + off];
        __syncthreads();
    }
    if (t == 0) *flag = (s[0] > 8192) ? 1 : 0;  // 1 = inputs are bf16
}

// ---------- pack weight K x COLS into MFMA B-operand order ----------
// layout: dst[((kt*CT + ct)*64 + lane)*8 + j] = W[kt*32 + (lane>>4)*8 + j][ct*16 + (lane&15)]
template <int K, int COLS>
__global__ void k_packW(const void* __restrict__ src, unsigned short* __restrict__ dst,
                        const int* __restrict__ dflag) {
    constexpr int CT = COLS / 16;
    int i = blockIdx.x * 256 + threadIdx.x;
    if (i >= K * COLS) return;
    int j = i & 7;
    int lane = (i >> 3) & 63;
    int rest = i >> 9;
    int ct = rest % CT;
    int kt = rest / CT;
    int k = kt * 32 + (lane >> 4) * 8 + j;
    int c = ct * 16 + (lane & 15);
    int si = k * COLS + c;
    dst[i] = (*dflag) ? ((const unsigned short*)src)[si] : f2bf(((const float*)src)[si]);
}

// ---------- preprocessing: degree histogram, scan, counting sort ----------
__global__ void k_hist(const int* __restrict__ row, int* __restrict__ cnt, int E) {
    int e = blockIdx.x * 256 + threadIdx.x;
    if (e < E) {
        unsigned int r = (unsigned int)row[e];
        if (r >= NN) r = 0;
        atomicAdd(&cnt[r], 1);
    }
}

__global__ void k_scan_a(const int* __restrict__ cnt, int* __restrict__ bsum, int n) {
    __shared__ int s[256];
    int i = blockIdx.x * 256 + threadIdx.x;
    s[threadIdx.x] = (i < n) ? cnt[i] : 0;
    __syncthreads();
    for (int off = 128; off > 0; off >>= 1) {
        if (threadIdx.x < off) s[threadIdx.x] += s[threadIdx.x + off];
        __syncthreads();
    }
    if (threadIdx.x == 0) bsum[blockIdx.x] = s[0];
}

__global__ void k_scan_b(int* bsum, int nchunks) {
    __shared__ int s[512];
    int t = threadIdx.x;
    int v = (t < nchunks) ? bsum[t] : 0;
    s[t] = v;
    __syncthreads();
    for (int off = 1; off < 512; off <<= 1) {
        int x = (t >= off) ? s[t - off] : 0;
        __syncthreads();
        s[t] += x;
        __syncthreads();
    }
    if (t < nchunks) bsum[t] = s[t] - v;  // exclusive
}

__global__ void k_scan_c(const int* __restrict__ cnt, const int* __restrict__ bsum,
                         int* __restrict__ offs, int* __restrict__ cursor, int n) {
    __shared__ int s[256];
    int t = threadIdx.x;
    int i = blockIdx.x * 256 + t;
    int v = (i < n) ? cnt[i] : 0;
    s[t] = v;
    __syncthreads();
    for (int off = 1; off < 256; off <<= 1) {
        int x = (t >= off) ? s[t - off] : 0;
        __syncthreads();
        s[t] += x;
        __syncthreads();
    }
    if (i < n) {
        int ex = bsum[blockIdx.x] + s[t] - v;
        offs[i] = ex;
        cursor[i] = ex;
    }
}

__global__ void k_scatter(const int* __restrict__ row, const int* __restrict__ col,
                          int* __restrict__ cursor, int* __restrict__ colS, int E) {
    int e = blockIdx.x * 256 + threadIdx.x;
    if (e < E) {
        unsigned int r = (unsigned int)row[e];
        if (r >= NN) r = 0;
        unsigned int c = (unsigned int)col[e];
        if (c >= NN) c = 0;
        int p = atomicAdd(&cursor[r], 1);
        colS[p] = (int)c;
    }
}

__global__ void k_dinv(const int* __restrict__ cnt, float* __restrict__ dinv, int n) {
    int i = blockIdx.x * 256 + threadIdx.x;
    if (i < n) dinv[i] = rsqrtf((float)(cnt[i] + 1));  // +1 self loop
}

// ---------- MFMA GEMM: G[r][c] = dinv[r] * sum_k relu?(A[r][k]) * W[k][c]; G bf16 ----------
// AMODE 0: A bf16. AMODE 2: A dtype per dflag (layer 0; fp32 path converts in-flight).
// Wave computes 16 rows x COLS via 16x16x32 bf16 MFMA. Block = 4 waves = 64 rows.
template <int K, int COLS, bool RELU, int AMODE>
__global__ __launch_bounds__(256) void k_gemm(const void* __restrict__ Av,
                                              const unsigned short* __restrict__ Wp,
                                              const float* __restrict__ dinv,
                                              unsigned short* __restrict__ G, int nrows,
                                              const int* __restrict__ dflag) {
    constexpr int CT = COLS / 16;
    constexpr int KT = K / 32;
    // per-wave LDS tile; row stride 136 ushort (272B) keeps 16B alignment for b128
    __shared__ unsigned short tile[4][16][136];

    int t = threadIdx.x;
    int wave = t >> 6, lane = t & 63;
    int quad = lane >> 4, m = lane & 15;
    int r0 = blockIdx.x * 64 + wave * 16;
    int arow = r0 + m;
    bool rowok = arow < nrows;
    bool abf = (AMODE == 0) || (*dflag != 0);

    const unsigned short* Ab = (const unsigned short*)Av;
    const float* Af = (const float*)Av;

    f32x4 acc[CT];
#pragma unroll
    for (int ct = 0; ct < CT; ct++) acc[ct] = (f32x4){0.f, 0.f, 0.f, 0.f};

    for (int kt = 0; kt < KT; kt++) {
        int kb = kt * 32 + quad * 8;
        bf16x8 afrag = (bf16x8)0;
        if (rowok) {
            if (abf) {
                afrag = *(const bf16x8*)(Ab + (size_t)arow * K + kb);
                if constexpr (RELU) {
#pragma unroll
                    for (int j = 0; j < 8; j++) {
                        unsigned short u = (unsigned short)afrag[j];
                        afrag[j] = (u & 0x8000u) ? (short)0 : (short)u;
                    }
                }
            } else {
                float4 f0 = *(const float4*)(Af + (size_t)arow * K + kb);
                float4 f1 = *(const float4*)(Af + (size_t)arow * K + kb + 4);
                afrag[0] = (short)f2bf(f0.x); afrag[1] = (short)f2bf(f0.y);
                afrag[2] = (short)f2bf(f0.z); afrag[3] = (short)f2bf(f0.w);
                afrag[4] = (short)f2bf(f1.x); afrag[5] = (short)f2bf(f1.y);
                afrag[6] = (short)f2bf(f1.z); afrag[7] = (short)f2bf(f1.w);
            }
        }
#pragma unroll
        for (int ct = 0; ct < CT; ct++) {
            bf16x8 bfrag = *(const bf16x8*)(Wp + (((size_t)kt * CT + ct) * 64 + lane) * 8);
            acc[ct] = __builtin_amdgcn_mfma_f32_16x16x32_bf16(afrag, bfrag, acc[ct], 0, 0, 0);
        }
    }

    // epilogue: scale by dinv (C layout: col=lane&15, row=quad*4+reg), via LDS to coalesce
    float dv[4];
#pragma unroll
    for (int rg = 0; rg < 4; rg++) {
        int gr = r0 + quad * 4 + rg;
        dv[rg] = dinv[gr < nrows ? gr : 0];
    }
#pragma unroll
    for (int ct = 0; ct < CT; ct++) {
#pragma unroll
        for (int rg = 0; rg < 4; rg++)
            tile[wave][quad * 4 + rg][ct * 16 + m] = f2bf(acc[ct][rg] * dv[rg]);
    }
    // wave-private LDS: compiler inserts lgkmcnt wait; no __syncthreads needed
    int srow = lane >> 2;
    int grow = r0 + srow;
    if (grow < nrows) {
        constexpr int CH = COLS / 32;  // 16B chunks per lane
#pragma unroll
        for (int j8 = 0; j8 < CH; j8++) {
            int c = (lane & 3) * 8 + j8 * 32;  // 4 lanes cover 64B contiguous per row
            uint4 v = *(const uint4*)&tile[wave][srow][c];
            *(uint4*)(G + (size_t)grow * COLS + c) = v;
        }
    }
}

// ---------- aggregate: out[r] = relu?(dinv[r]*(g[r] + sum_{c in adj(r)} g[c])) ----------
template <int D, bool RELU, bool FINAL>
__global__ __launch_bounds__(256) void k_agg(const unsigned short* __restrict__ g,
                                             const int* __restrict__ colS,
                                             const int* __restrict__ offs,
                                             const int* __restrict__ cnt,
                                             const float* __restrict__ dinv,
                                             unsigned short* __restrict__ obf,
                                             void* __restrict__ oraw,
                                             const int* __restrict__ dflag, int n) {
    int lane = threadIdx.x & 63;
    int node = blockIdx.x * 4 + (threadIdx.x >> 6);
    if (node >= n) return;
    int start = offs[node];
    int deg = cnt[node];

    float a0 = 0.f, a1 = 0.f;
    if constexpr (D == 128) {
        unsigned int u = *(const unsigned int*)(g + (size_t)node * 128 + lane * 2);
        a0 = bf2f(u); a1 = bf2f(u >> 16);
    } else {
        a0 = bf2f(g[(size_t)node * 64 + lane]);
    }

    for (int base = 0; base < deg; base += 64) {
        int rem = deg - base;
        int nb = rem < 64 ? rem : 64;
        int cidx = 0;
        if (lane < nb) cidx = colS[start + base + lane];
        int j = 0;
        for (; j + 4 <= nb; j += 4) {
            int c0 = __shfl(cidx, j);
            int c1 = __shfl(cidx, j + 1);
            int c2 = __shfl(cidx, j + 2);
            int c3 = __shfl(cidx, j + 3);
            if constexpr (D == 128) {
                unsigned int u0 = *(const unsigned int*)(g + (size_t)c0 * 128 + lane * 2);
                unsigned int u1 = *(const unsigned int*)(g + (size_t)c1 * 128 + lane * 2);
                unsigned int u2 = *(const unsigned int*)(g + (size_t)c2 * 128 + lane * 2);
                unsigned int u3 = *(const unsigned int*)(g + (size_t)c3 * 128 + lane * 2);
                a0 += bf2f(u0); a1 += bf2f(u0 >> 16);
                a0 += bf2f(u1); a1 += bf2f(u1 >> 16);
                a0 += bf2f(u2); a1 += bf2f(u2 >> 16);
                a0 += bf2f(u3); a1 += bf2f(u3 >> 16);
            } else {
                unsigned short u0 = g[(size_t)c0 * 64 + lane];
                unsigned short u1 = g[(size_t)c1 * 64 + lane];
                unsigned short u2 = g[(size_t)c2 * 64 + lane];
                unsigned short u3 = g[(size_t)c3 * 64 + lane];
                a0 += bf2f(u0) + bf2f(u1) + bf2f(u2) + bf2f(u3);
            }
        }
        for (; j < nb; j++) {
            int cj = __shfl(cidx, j);
            if constexpr (D == 128) {
                unsigned int u = *(const unsigned int*)(g + (size_t)cj * 128 + lane * 2);
                a0 += bf2f(u); a1 += bf2f(u >> 16);
            } else {
                a0 += bf2f(g[(size_t)cj * 64 + lane]);
            }
        }
    }

    float s = dinv[node];
    a0 *= s; a1 *= s;
    if constexpr (RELU) { a0 = fmaxf(a0, 0.f); a1 = fmaxf(a1, 0.f); }

    if constexpr (D == 128) {
        *(unsigned int*)(obf + (size_t)node * 128 + lane * 2) =
            (unsigned int)f2bf(a0) | ((unsigned int)f2bf(a1) << 16);
    } else {
        obf[(size_t)node * 64 + lane] = f2bf(a0);
        if constexpr (FINAL) {
            if (*dflag) ((unsigned short*)oraw)[(size_t)node * 64 + lane] = f2bf(a0);
            else        ((float*)oraw)[(size_t)node * 64 + lane] = a0;
        }
    }
}

// ---------- correlation metric (bf16 input) ----------
template <int D>
__global__ void k_colsum(const unsigned short* __restrict__ in, float* __restrict__ colsum, int n) {
    int t = threadIdx.x;
    int c = t % D;
    constexpr int RPB = 256 / D;
    int r = blockIdx.x * RPB + t / D;
    int stride = gridDim.x * RPB;
    float s = 0.f;
    for (; r < n; r += stride) s += bf2f(in[(size_t)r * D + c]);
    atomicAdd(&colsum[c], s);
}

template <int D>
__global__ __launch_bounds__(256) void k_cov(const unsigned short* __restrict__ in,
                                             const float* __restrict__ colsum,
                                             float* __restrict__ cov, int n) {
    constexpr int TI = D / 16;
    __shared__ float rb[16][D];
    __shared__ float smean[D];
    int t = threadIdx.x;
    if (t < D) smean[t] = colsum[t] * (1.0f / (float)NN);
    __syncthreads();

    float acc[TI * TI];
#pragma unroll
    for (int q = 0; q < TI * TI; q++) acc[q] = 0.f;
    int i0 = (t >> 4) * TI;
    int j0 = (t & 15) * TI;

    for (int base = blockIdx.x * 16; base < n; base += gridDim.x * 16) {
        for (int idx = t; idx < 16 * D; idx += 256) {
            int r = idx / D, c = idx % D;
            rb[r][c] = bf2f(in[(size_t)(base + r) * D + c]) - smean[c];
        }
        __syncthreads();
#pragma unroll
        for (int r = 0; r < 16; r++) {
            float ai[TI], aj[TI];
#pragma unroll
            for (int q = 0; q < TI; q += 4) {
                *(float4*)&ai[q] = *(const float4*)&rb[r][i0 + q];
                *(float4*)&aj[q] = *(const float4*)&rb[r][j0 + q];
            }
#pragma unroll
            for (int ii = 0; ii < TI; ii++)
#pragma unroll
                for (int jj = 0; jj < TI; jj++) acc[ii * TI + jj] += ai[ii] * aj[jj];
        }
        __syncthreads();
    }
#pragma unroll
    for (int ii = 0; ii < TI; ii++)
#pragma unroll
        for (int jj = 0; jj < TI; jj++)
            atomicAdd(&cov[(i0 + ii) * D + (j0 + jj)], acc[ii * TI + jj]);
}

template <int D>
__global__ __launch_bounds__(256) void k_fin(const float* __restrict__ cov,
                                             void* __restrict__ out, long long idx,
                                             const int* __restrict__ dflag) {
    __shared__ float sd[D];
    __shared__ float red[256];
    int t = threadIdx.x;
    if (t < D) sd[t] = sqrtf(fmaxf(cov[t * D + t], 1e-12f));
    __syncthreads();
    float s = 0.f;
    for (int i2 = t; i2 < D * D; i2 += 256) {
        int i = i2 / D, j = i2 % D;
        if (j > i) s += fabsf(cov[i2] / (sd[i] * sd[j]));
    }
    red[t] = s;
    __syncthreads();
    for (int off = 128; off > 0; off >>= 1) {
        if (t < off) red[t] += red[t + off];
        __syncthreads();
    }
    if (t == 0) {
        float v = red[0] / (float)(D * (D - 1) / 2);
        if (*dflag) ((unsigned short*)out)[idx] = f2bf(v);
        else        ((float*)out)[idx] = v;
    }
}

// ---------- launch ----------
extern "C" void kernel_launch(void* const* d_in, const int* in_sizes, int n_in,
                              void* d_out, int out_size, void* d_ws, size_t ws_size,
                              hipStream_t stream) {
    const void* x = d_in[0];
    const int* ei = (const int*)d_in[1];

    int E = in_sizes[1] / 2;
    const int* row = ei;
    const int* col = ei + E;

    char* w = (char*)d_ws;
    auto carve = [&](size_t bytes) {
        void* p = (void*)w;
        w += (bytes + 255) & ~(size_t)255;
        return p;
    };
    int* cnt = (int*)carve((size_t)NN * 4);
    int* offs = (int*)carve((size_t)NN * 4);
    int* cursor = (int*)carve((size_t)NN * 4);
    int* bsum = (int*)carve(512 * 4);
    int* colS = (int*)carve((size_t)E * 4);
    float* dinv = (float*)carve((size_t)NN * 4);
    float* colsum = (float*)carve(HD * 4);
    float* covs = (float*)carve(HD * HD * 4);
    int* dflag = (int*)carve(256);
    unsigned short* wc = (unsigned short*)carve((size_t)(FIN * HD + HD * HD * 2 + HD * CD) * 2);
    unsigned short* bufA = (unsigned short*)carve((size_t)NN * HD * 2);
    unsigned short* bufB = (unsigned short*)carve((size_t)NN * HD * 2);

    unsigned short* wc0 = wc;              // 256x128 packed
    unsigned short* wc1 = wc + FIN * HD;   // 128x128 packed
    unsigned short* wc2 = wc1 + HD * HD;   // 128x128 packed
    unsigned short* wc3 = wc2 + HD * HD;   // 128x64 packed

    int nchunks = (NN + 255) / 256;
    int eblocks = (E + 255) / 256;
    int GB = (NN + 63) / 64;  // gemm blocks (64 rows each)

    // dtype detection + weight packing (MFMA B-operand layout)
    k_detect<<<1, 256, 0, stream>>>((const unsigned short*)x, dflag);
    k_packW<256, 128><<<(FIN * HD) / 256, 256, 0, stream>>>(d_in[2], wc0, dflag);
    k_packW<128, 128><<<(HD * HD) / 256, 256, 0, stream>>>(d_in[3], wc1, dflag);
    k_packW<128, 128><<<(HD * HD) / 256, 256, 0, stream>>>(d_in[4], wc2, dflag);
    k_packW<128, 64><<<(HD * CD) / 256, 256, 0, stream>>>(d_in[5], wc3, dflag);

    // preprocessing (CSR by destination)
    hipMemsetAsync(cnt, 0, (size_t)NN * 4, stream);
    k_hist<<<eblocks, 256, 0, stream>>>(row, cnt, E);
    k_scan_a<<<nchunks, 256, 0, stream>>>(cnt, bsum, NN);
    k_scan_b<<<1, 512, 0, stream>>>(bsum, nchunks);
    k_scan_c<<<nchunks, 256, 0, stream>>>(cnt, bsum, offs, cursor, NN);
    k_scatter<<<eblocks, 256, 0, stream>>>(row, col, cursor, colS, E);
    k_dinv<<<nchunks, 256, 0, stream>>>(cnt, dinv, NN);

    // layer 0: x @ W0 -> B ; aggregate -> A (relu)
    k_gemm<256, 128, false, 2><<<GB, 256, 0, stream>>>(x, wc0, dinv, bufB, NN, dflag);
    k_agg<128, true, false><<<NN / 4, 256, 0, stream>>>(bufB, colS, offs, cnt, dinv, bufA, nullptr, dflag, NN);
    // layer 1
    k_gemm<128, 128, false, 0><<<GB, 256, 0, stream>>>(bufA, wc1, dinv, bufB, NN, dflag);
    k_agg<128, true, false><<<NN / 4, 256, 0, stream>>>(bufB, colS, offs, cnt, dinv, bufA, nullptr, dflag, NN);
    // layer 2 (pre-ReLU kept in bufA for corr_2)
    k_gemm<128, 128, false, 0><<<GB, 256, 0, stream>>>(bufA, wc2, dinv, bufB, NN, dflag);
    k_agg<128, false, false><<<NN / 4, 256, 0, stream>>>(bufB, colS, offs, cnt, dinv, bufA, nullptr, dflag, NN);

    // corr_2 on bufA (bf16, D=128)
    hipMemsetAsync(colsum, 0, HD * 4, stream);
    hipMemsetAsync(covs, 0, HD * HD * 4, stream);
    k_colsum<128><<<128, 256, 0, stream>>>(bufA, colsum, NN);
    k_cov<128><<<256, 256, 0, stream>>>(bufA, colsum, covs, NN);
    k_fin<128><<<1, 256, 0, stream>>>(covs, d_out, (long long)NN * CD, dflag);

    // layer 3: relu(bufA) @ W3 -> B ; aggregate -> d_out (+ bf16 mirror in bufA)
    k_gemm<128, 64, true, 0><<<GB, 256, 0, stream>>>(bufA, wc3, dinv, bufB, NN, dflag);
    k_agg<64, false, true><<<NN / 4, 256, 0, stream>>>(bufB, colS, offs, cnt, dinv, bufA, d_out, dflag, NN);

    // corr on final output (bf16 mirror, D=64)
    hipMemsetAsync(colsum, 0, HD * 4, stream);
    hipMemsetAsync(covs, 0, HD * HD * 4, stream);
    k_colsum<64><<<128, 256, 0, stream>>>(bufA, colsum, NN);
    k_cov<64><<<256, 256, 0, stream>>>(bufA, colsum, covs, NN);
    k_fin<64><<<1, 256, 0, stream>>>(covs, d_out, (long long)NN * CD + 1, dflag);
}

// Round 5
// 1133.409 us; speedup vs baseline: 1.5535x; 1.1080x over previous
//
#include <hip/hip_runtime.h>

#define NN 100000
#define FIN 256
#define HD 128
#define CD 64

typedef __attribute__((ext_vector_type(8))) short bf16x8;
typedef __attribute__((ext_vector_type(4))) float f32x4;

// ---------- bf16 helpers ----------
__device__ __forceinline__ float bf2f(unsigned int u16) {
    union { unsigned int u; float f; } v;
    v.u = (u16 & 0xffffu) << 16;
    return v.f;
}
__device__ __forceinline__ unsigned short f2bf(float f) {
    union { float f; unsigned int u; } v;
    v.f = f;
    unsigned int u = v.u + 0x7fffu + ((v.u >> 16) & 1u);  // RNE
    return (unsigned short)(u >> 16);
}

// ---------- dtype detection (inputs bf16 vs fp32; measured R3: fp32) ----------
__global__ void k_detect(const unsigned short* __restrict__ x, int* __restrict__ flag) {
    __shared__ int s[256];
    int t = threadIdx.x;
    int c = 0;
    for (int i = t; i < 16384; i += 256) {
        unsigned int e = (x[2 * i] >> 7) & 0xFF;
        c += (e >= 112 && e <= 134) ? 1 : 0;
    }
    s[t] = c;
    __syncthreads();
    for (int off = 128; off > 0; off >>= 1) {
        if (t < off) s[t] += s[t + off];
        __syncthreads();
    }
    if (t == 0) *flag = (s[0] > 8192) ? 1 : 0;  // 1 = inputs are bf16
}

// ---------- pack weight K x COLS into MFMA B-operand order ----------
template <int K, int COLS>
__global__ void k_packW(const void* __restrict__ src, unsigned short* __restrict__ dst,
                        const int* __restrict__ dflag) {
    constexpr int CT = COLS / 16;
    int i = blockIdx.x * 256 + threadIdx.x;
    if (i >= K * COLS) return;
    int j = i & 7;
    int lane = (i >> 3) & 63;
    int rest = i >> 9;
    int ct = rest % CT;
    int kt = rest / CT;
    int k = kt * 32 + (lane >> 4) * 8 + j;
    int c = ct * 16 + (lane & 15);
    int si = k * COLS + c;
    dst[i] = (*dflag) ? ((const unsigned short*)src)[si] : f2bf(((const float*)src)[si]);
}

// ---------- preprocessing: degree histogram, scan, counting sort ----------
__global__ void k_hist(const int* __restrict__ row, int* __restrict__ cnt, int E) {
    int e = blockIdx.x * 256 + threadIdx.x;
    if (e < E) {
        unsigned int r = (unsigned int)row[e];
        if (r >= NN) r = 0;
        atomicAdd(&cnt[r], 1);
    }
}

__global__ void k_scan_a(const int* __restrict__ cnt, int* __restrict__ bsum, int n) {
    __shared__ int s[256];
    int i = blockIdx.x * 256 + threadIdx.x;
    s[threadIdx.x] = (i < n) ? cnt[i] : 0;
    __syncthreads();
    for (int off = 128; off > 0; off >>= 1) {
        if (threadIdx.x < off) s[threadIdx.x] += s[threadIdx.x + off];
        __syncthreads();
    }
    if (threadIdx.x == 0) bsum[blockIdx.x] = s[0];
}

__global__ void k_scan_b(int* bsum, int nchunks) {
    __shared__ int s[512];
    int t = threadIdx.x;
    int v = (t < nchunks) ? bsum[t] : 0;
    s[t] = v;
    __syncthreads();
    for (int off = 1; off < 512; off <<= 1) {
        int x = (t >= off) ? s[t - off] : 0;
        __syncthreads();
        s[t] += x;
        __syncthreads();
    }
    if (t < nchunks) bsum[t] = s[t] - v;  // exclusive
}

__global__ void k_scan_c(const int* __restrict__ cnt, const int* __restrict__ bsum,
                         int* __restrict__ offs, int* __restrict__ cursor, int n) {
    __shared__ int s[256];
    int t = threadIdx.x;
    int i = blockIdx.x * 256 + t;
    int v = (i < n) ? cnt[i] : 0;
    s[t] = v;
    __syncthreads();
    for (int off = 1; off < 256; off <<= 1) {
        int x = (t >= off) ? s[t - off] : 0;
        __syncthreads();
        s[t] += x;
        __syncthreads();
    }
    if (i < n) {
        int ex = bsum[blockIdx.x] + s[t] - v;
        offs[i] = ex;
        cursor[i] = ex;
    }
}

__global__ void k_scatter(const int* __restrict__ row, const int* __restrict__ col,
                          int* __restrict__ cursor, int* __restrict__ colS, int E) {
    int e = blockIdx.x * 256 + threadIdx.x;
    if (e < E) {
        unsigned int r = (unsigned int)row[e];
        if (r >= NN) r = 0;
        unsigned int c = (unsigned int)col[e];
        if (c >= NN) c = 0;
        int p = atomicAdd(&cursor[r], 1);
        colS[p] = (int)c;
    }
}

__global__ void k_dinv(const int* __restrict__ cnt, float* __restrict__ dinv, int n) {
    int i = blockIdx.x * 256 + threadIdx.x;
    if (i < n) dinv[i] = rsqrtf((float)(cnt[i] + 1));  // +1 self loop
}

// ---------- MFMA GEMM: G[r][c] = dinv[r] * sum_k relu?(A[r][k]) * W[k][c]; G bf16 ----------
template <int K, int COLS, bool RELU, int AMODE>
__global__ __launch_bounds__(256) void k_gemm(const void* __restrict__ Av,
                                              const unsigned short* __restrict__ Wp,
                                              const float* __restrict__ dinv,
                                              unsigned short* __restrict__ G, int nrows,
                                              const int* __restrict__ dflag) {
    constexpr int CT = COLS / 16;
    constexpr int KT = K / 32;
    __shared__ unsigned short tile[4][16][136];

    int t = threadIdx.x;
    int wave = t >> 6, lane = t & 63;
    int quad = lane >> 4, m = lane & 15;
    int r0 = blockIdx.x * 64 + wave * 16;
    int arow = r0 + m;
    bool rowok = arow < nrows;
    bool abf = (AMODE == 0) || (*dflag != 0);

    const unsigned short* Ab = (const unsigned short*)Av;
    const float* Af = (const float*)Av;

    f32x4 acc[CT];
#pragma unroll
    for (int ct = 0; ct < CT; ct++) acc[ct] = (f32x4){0.f, 0.f, 0.f, 0.f};

    for (int kt = 0; kt < KT; kt++) {
        int kb = kt * 32 + quad * 8;
        bf16x8 afrag = (bf16x8)0;
        if (rowok) {
            if (abf) {
                afrag = *(const bf16x8*)(Ab + (size_t)arow * K + kb);
                if constexpr (RELU) {
#pragma unroll
                    for (int j = 0; j < 8; j++) {
                        unsigned short u = (unsigned short)afrag[j];
                        afrag[j] = (u & 0x8000u) ? (short)0 : (short)u;
                    }
                }
            } else {
                float4 f0 = *(const float4*)(Af + (size_t)arow * K + kb);
                float4 f1 = *(const float4*)(Af + (size_t)arow * K + kb + 4);
                afrag[0] = (short)f2bf(f0.x); afrag[1] = (short)f2bf(f0.y);
                afrag[2] = (short)f2bf(f0.z); afrag[3] = (short)f2bf(f0.w);
                afrag[4] = (short)f2bf(f1.x); afrag[5] = (short)f2bf(f1.y);
                afrag[6] = (short)f2bf(f1.z); afrag[7] = (short)f2bf(f1.w);
            }
        }
#pragma unroll
        for (int ct = 0; ct < CT; ct++) {
            bf16x8 bfrag = *(const bf16x8*)(Wp + (((size_t)kt * CT + ct) * 64 + lane) * 8);
            acc[ct] = __builtin_amdgcn_mfma_f32_16x16x32_bf16(afrag, bfrag, acc[ct], 0, 0, 0);
        }
    }

    float dv[4];
#pragma unroll
    for (int rg = 0; rg < 4; rg++) {
        int gr = r0 + quad * 4 + rg;
        dv[rg] = dinv[gr < nrows ? gr : 0];
    }
#pragma unroll
    for (int ct = 0; ct < CT; ct++) {
#pragma unroll
        for (int rg = 0; rg < 4; rg++)
            tile[wave][quad * 4 + rg][ct * 16 + m] = f2bf(acc[ct][rg] * dv[rg]);
    }
    int srow = lane >> 2;
    int grow = r0 + srow;
    if (grow < nrows) {
        constexpr int CH = COLS / 32;
#pragma unroll
        for (int j8 = 0; j8 < CH; j8++) {
            int c = (lane & 3) * 8 + j8 * 32;
            uint4 v = *(const uint4*)&tile[wave][srow][c];
            *(uint4*)(G + (size_t)grow * COLS + c) = v;
        }
    }
}

// ---------- aggregate: out[r] = relu?(dinv[r]*(g[r] + sum_{c in adj(r)} g[c])) ----------
template <int D, bool RELU, bool FINAL>
__global__ __launch_bounds__(256) void k_agg(const unsigned short* __restrict__ g,
                                             const int* __restrict__ colS,
                                             const int* __restrict__ offs,
                                             const int* __restrict__ cnt,
                                             const float* __restrict__ dinv,
                                             unsigned short* __restrict__ obf,
                                             void* __restrict__ oraw,
                                             const int* __restrict__ dflag, int n) {
    int lane = threadIdx.x & 63;
    int node = blockIdx.x * 4 + (threadIdx.x >> 6);
    if (node >= n) return;
    int start = offs[node];
    int deg = cnt[node];

    float a0 = 0.f, a1 = 0.f;
    if constexpr (D == 128) {
        unsigned int u = *(const unsigned int*)(g + (size_t)node * 128 + lane * 2);
        a0 = bf2f(u); a1 = bf2f(u >> 16);
    } else {
        a0 = bf2f(g[(size_t)node * 64 + lane]);
    }

    for (int base = 0; base < deg; base += 64) {
        int rem = deg - base;
        int nb = rem < 64 ? rem : 64;
        int cidx = 0;
        if (lane < nb) cidx = colS[start + base + lane];
        int j = 0;
        for (; j + 4 <= nb; j += 4) {
            int c0 = __shfl(cidx, j);
            int c1 = __shfl(cidx, j + 1);
            int c2 = __shfl(cidx, j + 2);
            int c3 = __shfl(cidx, j + 3);
            if constexpr (D == 128) {
                unsigned int u0 = *(const unsigned int*)(g + (size_t)c0 * 128 + lane * 2);
                unsigned int u1 = *(const unsigned int*)(g + (size_t)c1 * 128 + lane * 2);
                unsigned int u2 = *(const unsigned int*)(g + (size_t)c2 * 128 + lane * 2);
                unsigned int u3 = *(const unsigned int*)(g + (size_t)c3 * 128 + lane * 2);
                a0 += bf2f(u0); a1 += bf2f(u0 >> 16);
                a0 += bf2f(u1); a1 += bf2f(u1 >> 16);
                a0 += bf2f(u2); a1 += bf2f(u2 >> 16);
                a0 += bf2f(u3); a1 += bf2f(u3 >> 16);
            } else {
                unsigned short u0 = g[(size_t)c0 * 64 + lane];
                unsigned short u1 = g[(size_t)c1 * 64 + lane];
                unsigned short u2 = g[(size_t)c2 * 64 + lane];
                unsigned short u3 = g[(size_t)c3 * 64 + lane];
                a0 += bf2f(u0) + bf2f(u1) + bf2f(u2) + bf2f(u3);
            }
        }
        for (; j < nb; j++) {
            int cj = __shfl(cidx, j);
            if constexpr (D == 128) {
                unsigned int u = *(const unsigned int*)(g + (size_t)cj * 128 + lane * 2);
                a0 += bf2f(u); a1 += bf2f(u >> 16);
            } else {
                a0 += bf2f(g[(size_t)cj * 64 + lane]);
            }
        }
    }

    float s = dinv[node];
    a0 *= s; a1 *= s;
    if constexpr (RELU) { a0 = fmaxf(a0, 0.f); a1 = fmaxf(a1, 0.f); }

    if constexpr (D == 128) {
        *(unsigned int*)(obf + (size_t)node * 128 + lane * 2) =
            (unsigned int)f2bf(a0) | ((unsigned int)f2bf(a1) << 16);
    } else {
        obf[(size_t)node * 64 + lane] = f2bf(a0);
        if constexpr (FINAL) {
            if (*dflag) ((unsigned short*)oraw)[(size_t)node * 64 + lane] = f2bf(a0);
            else        ((float*)oraw)[(size_t)node * 64 + lane] = a0;
        }
    }
}

// ---------- column sums (vectorized bf16x8 loads + LDS reduce) ----------
template <int D>
__global__ __launch_bounds__(256) void k_colsum(const unsigned short* __restrict__ in,
                                                float* __restrict__ colsum, int n) {
    constexpr int CG = D / 8;        // 16 or 8
    constexpr int RPB = 256 / CG;    // 16 or 32
    __shared__ float red[RPB][D];
    int t = threadIdx.x;
    int cg = t % CG, r0 = t / CG;
    int c0 = cg * 8;
    float a[8];
#pragma unroll
    for (int i = 0; i < 8; i++) a[i] = 0.f;
    for (int r = blockIdx.x * RPB + r0; r < n; r += gridDim.x * RPB) {
        bf16x8 u = *(const bf16x8*)(in + (size_t)r * D + c0);
#pragma unroll
        for (int i = 0; i < 8; i++) a[i] += bf2f((unsigned short)u[i]);
    }
#pragma unroll
    for (int i = 0; i < 8; i++) red[r0][c0 + i] = a[i];
    __syncthreads();
    if (t < D) {
        float s = 0.f;
#pragma unroll
        for (int r = 0; r < RPB; r++) s += red[r][t];
        atomicAdd(&colsum[t], s);
    }
}

// ---------- MFMA covariance: part[b] += Hc^T Hc over this block's K-chunks ----------
// Hc = bf16(h - mean). Staged transposed in LDS as packed (k,k+1) dwords with a
// rotation swizzle: word slot = ((kp>>2 + (c>>3)) & 3)*4 + (kp&3); 16B-aligned b128
// fragment reads, ~4-way worst conflicts. A-frag and B-frag lane patterns coincide
// (C symmetric), so one fragment set serves both MFMA operands.
template <int D>
__global__ __launch_bounds__(256) void k_cov2(const unsigned short* __restrict__ in,
                                              const float* __restrict__ colsum,
                                              float* __restrict__ part, int n, int nblocks) {
    constexpr int CT = D / 16;               // tile cols: 8 (D=128) or 4 (D=64)
    constexpr int TPW = (D == 128) ? 2 : 1;  // tile rows per wave
    __shared__ unsigned int lds32[D * 16];
    __shared__ float smean[D];

    int t = threadIdx.x;
    int wave = t >> 6, lane = t & 63;
    int quad = lane >> 4, m = lane & 15;

    if (t < D) smean[t] = colsum[t] * (1.0f / (float)NN);
    __syncthreads();

    f32x4 acc[TPW][CT];
#pragma unroll
    for (int q = 0; q < TPW; q++)
#pragma unroll
        for (int tc = 0; tc < CT; tc++) acc[q][tc] = (f32x4){0.f, 0.f, 0.f, 0.f};

    constexpr int CG = D / 8;  // c-groups per row
    int nchunks = (n + 31) / 32;
    for (int ch = blockIdx.x; ch < nchunks; ch += nblocks) {
        int k0 = ch * 32;
        if (t < 16 * CG) {
            int kp = t / CG;
            int c0 = (t % CG) * 8;
            int k = k0 + 2 * kp;
            bf16x8 u0 = (bf16x8)0, u1 = (bf16x8)0;
            bool ok0 = (k < n), ok1 = (k + 1 < n);
            if (ok0) u0 = *(const bf16x8*)(in + (size_t)k * D + c0);
            if (ok1) u1 = *(const bf16x8*)(in + (size_t)(k + 1) * D + c0);
#pragma unroll
            for (int i = 0; i < 8; i++) {
                int c = c0 + i;
                float a = ok0 ? (bf2f((unsigned short)u0[i]) - smean[c]) : 0.f;
                float b = ok1 ? (bf2f((unsigned short)u1[i]) - smean[c]) : 0.f;
                int slot = ((((kp >> 2) + (c >> 3)) & 3) << 2) | (kp & 3);
                lds32[c * 16 + slot] = (unsigned int)f2bf(a) | ((unsigned int)f2bf(b) << 16);
            }
        }
        __syncthreads();
        bf16x8 frag[CT];
#pragma unroll
        for (int tc = 0; tc < CT; tc++) {
            int c = tc * 16 + m;
            int grp = (quad + (c >> 3)) & 3;
            frag[tc] = *(const bf16x8*)&lds32[c * 16 + grp * 4];
        }
#pragma unroll
        for (int q = 0; q < TPW; q++) {
            int tr = wave * TPW + q;
#pragma unroll
            for (int tc = 0; tc < CT; tc++)
                acc[q][tc] = __builtin_amdgcn_mfma_f32_16x16x32_bf16(frag[tr], frag[tc],
                                                                     acc[q][tc], 0, 0, 0);
        }
        __syncthreads();
    }

    float* p = part + (size_t)blockIdx.x * D * D;
#pragma unroll
    for (int q = 0; q < TPW; q++) {
        int tr = wave * TPW + q;
#pragma unroll
        for (int tc = 0; tc < CT; tc++)
#pragma unroll
            for (int rg = 0; rg < 4; rg++) {
                int ri = tr * 16 + quad * 4 + rg;
                int cj = tc * 16 + m;
                p[ri * D + cj] = acc[q][tc][rg];
            }
    }
}

template <int D>
__global__ void k_covred(const float* __restrict__ part, float* __restrict__ cov, int nblocks) {
    int idx = blockIdx.x * 256 + threadIdx.x;
    if (idx >= D * D) return;
    float s = 0.f;
    for (int b = 0; b < nblocks; b++) s += part[(size_t)b * D * D + idx];
    cov[idx] = s;
}

template <int D>
__global__ __launch_bounds__(256) void k_fin(const float* __restrict__ cov,
                                             void* __restrict__ out, long long idx,
                                             const int* __restrict__ dflag) {
    __shared__ float sd[D];
    __shared__ float red[256];
    int t = threadIdx.x;
    if (t < D) sd[t] = sqrtf(fmaxf(cov[t * D + t], 1e-12f));
    __syncthreads();
    float s = 0.f;
    for (int i2 = t; i2 < D * D; i2 += 256) {
        int i = i2 / D, j = i2 % D;
        if (j > i) s += fabsf(cov[i2] / (sd[i] * sd[j]));
    }
    red[t] = s;
    __syncthreads();
    for (int off = 128; off > 0; off >>= 1) {
        if (t < off) red[t] += red[t + off];
        __syncthreads();
    }
    if (t == 0) {
        float v = red[0] / (float)(D * (D - 1) / 2);
        if (*dflag) ((unsigned short*)out)[idx] = f2bf(v);
        else        ((float*)out)[idx] = v;
    }
}

// ---------- launch ----------
extern "C" void kernel_launch(void* const* d_in, const int* in_sizes, int n_in,
                              void* d_out, int out_size, void* d_ws, size_t ws_size,
                              hipStream_t stream) {
    const void* x = d_in[0];
    const int* ei = (const int*)d_in[1];

    int E = in_sizes[1] / 2;
    const int* row = ei;
    const int* col = ei + E;

    char* w = (char*)d_ws;
    auto carve = [&](size_t bytes) {
        void* p = (void*)w;
        w += (bytes + 255) & ~(size_t)255;
        return p;
    };
    int* cnt = (int*)carve((size_t)NN * 4);
    int* offs = (int*)carve((size_t)NN * 4);
    int* cursor = (int*)carve((size_t)NN * 4);
    int* bsum = (int*)carve(512 * 4);
    int* colS = (int*)carve((size_t)E * 4);
    float* dinv = (float*)carve((size_t)NN * 4);
    float* colsum = (float*)carve(HD * 4);
    float* covs = (float*)carve(HD * HD * 4);
    int* dflag = (int*)carve(256);
    unsigned short* wc = (unsigned short*)carve((size_t)(FIN * HD + HD * HD * 2 + HD * CD) * 2);
    unsigned short* bufA = (unsigned short*)carve((size_t)NN * HD * 2);
    unsigned short* bufB = (unsigned short*)carve((size_t)NN * HD * 2);

    unsigned short* wc0 = wc;              // 256x128 packed
    unsigned short* wc1 = wc + FIN * HD;   // 128x128 packed
    unsigned short* wc2 = wc1 + HD * HD;   // 128x128 packed
    unsigned short* wc3 = wc2 + HD * HD;   // 128x64 packed

    // cov partials alias bufB (dead during both corr computations)
    float* part = (float*)bufB;
    const int NBC = 125;  // 3125 K-chunks / 125 blocks = 25 each

    int nchunks = (NN + 255) / 256;
    int eblocks = (E + 255) / 256;
    int GB = (NN + 63) / 64;

    // dtype detection + weight packing
    k_detect<<<1, 256, 0, stream>>>((const unsigned short*)x, dflag);
    k_packW<256, 128><<<(FIN * HD) / 256, 256, 0, stream>>>(d_in[2], wc0, dflag);
    k_packW<128, 128><<<(HD * HD) / 256, 256, 0, stream>>>(d_in[3], wc1, dflag);
    k_packW<128, 128><<<(HD * HD) / 256, 256, 0, stream>>>(d_in[4], wc2, dflag);
    k_packW<128, 64><<<(HD * CD) / 256, 256, 0, stream>>>(d_in[5], wc3, dflag);

    // preprocessing (CSR by destination)
    hipMemsetAsync(cnt, 0, (size_t)NN * 4, stream);
    k_hist<<<eblocks, 256, 0, stream>>>(row, cnt, E);
    k_scan_a<<<nchunks, 256, 0, stream>>>(cnt, bsum, NN);
    k_scan_b<<<1, 512, 0, stream>>>(bsum, nchunks);
    k_scan_c<<<nchunks, 256, 0, stream>>>(cnt, bsum, offs, cursor, NN);
    k_scatter<<<eblocks, 256, 0, stream>>>(row, col, cursor, colS, E);
    k_dinv<<<nchunks, 256, 0, stream>>>(cnt, dinv, NN);

    // layer 0
    k_gemm<256, 128, false, 2><<<GB, 256, 0, stream>>>(x, wc0, dinv, bufB, NN, dflag);
    k_agg<128, true, false><<<NN / 4, 256, 0, stream>>>(bufB, colS, offs, cnt, dinv, bufA, nullptr, dflag, NN);
    // layer 1
    k_gemm<128, 128, false, 0><<<GB, 256, 0, stream>>>(bufA, wc1, dinv, bufB, NN, dflag);
    k_agg<128, true, false><<<NN / 4, 256, 0, stream>>>(bufB, colS, offs, cnt, dinv, bufA, nullptr, dflag, NN);
    // layer 2 (pre-ReLU kept in bufA for corr_2)
    k_gemm<128, 128, false, 0><<<GB, 256, 0, stream>>>(bufA, wc2, dinv, bufB, NN, dflag);
    k_agg<128, false, false><<<NN / 4, 256, 0, stream>>>(bufB, colS, offs, cnt, dinv, bufA, nullptr, dflag, NN);

    // corr_2 on bufA (bf16, D=128): colsum -> MFMA cov partials (in bufB) -> reduce -> fin
    hipMemsetAsync(colsum, 0, HD * 4, stream);
    k_colsum<128><<<64, 256, 0, stream>>>(bufA, colsum, NN);
    k_cov2<128><<<NBC, 256, 0, stream>>>(bufA, colsum, part, NN, NBC);
    k_covred<128><<<(HD * HD + 255) / 256, 256, 0, stream>>>(part, covs, NBC);
    k_fin<128><<<1, 256, 0, stream>>>(covs, d_out, (long long)NN * CD, dflag);

    // layer 3: relu(bufA) @ W3 -> bufB ; aggregate -> d_out (+ bf16 mirror in bufA)
    k_gemm<128, 64, true, 0><<<GB, 256, 0, stream>>>(bufA, wc3, dinv, bufB, NN, dflag);
    k_agg<64, false, true><<<NN / 4, 256, 0, stream>>>(bufB, colS, offs, cnt, dinv, bufA, d_out, dflag, NN);

    // corr on final output (bf16 mirror in bufA, D=64)
    hipMemsetAsync(colsum, 0, HD * 4, stream);
    k_colsum<64><<<64, 256, 0, stream>>>(bufA, colsum, NN);
    k_cov2<64><<<NBC, 256, 0, stream>>>(bufA, colsum, part, NN, NBC);
    k_covred<64><<<(CD * CD + 255) / 256, 256, 0, stream>>>(part, covs, NBC);
    k_fin<64><<<1, 256, 0, stream>>>(covs, d_out, (long long)NN * CD + 1, dflag);
}

// Round 6
// 952.337 us; speedup vs baseline: 1.8488x; 1.1901x over previous
//
#include <hip/hip_runtime.h>

#define NN 100000
#define FIN 256
#define HD 128
#define CD 64

typedef __attribute__((ext_vector_type(8))) short bf16x8;
typedef __attribute__((ext_vector_type(4))) float f32x4;

// ---------- bf16 helpers ----------
__device__ __forceinline__ float bf2f(unsigned int u16) {
    union { unsigned int u; float f; } v;
    v.u = (u16 & 0xffffu) << 16;
    return v.f;
}
__device__ __forceinline__ unsigned short f2bf(float f) {
    union { float f; unsigned int u; } v;
    v.f = f;
    unsigned int u = v.u + 0x7fffu + ((v.u >> 16) & 1u);  // RNE
    return (unsigned short)(u >> 16);
}

// ---------- dtype detection (inputs bf16 vs fp32; measured R3: fp32) ----------
__global__ void k_detect(const unsigned short* __restrict__ x, int* __restrict__ flag) {
    __shared__ int s[256];
    int t = threadIdx.x;
    int c = 0;
    for (int i = t; i < 16384; i += 256) {
        unsigned int e = (x[2 * i] >> 7) & 0xFF;
        c += (e >= 112 && e <= 134) ? 1 : 0;
    }
    s[t] = c;
    __syncthreads();
    for (int off = 128; off > 0; off >>= 1) {
        if (t < off) s[t] += s[t + off];
        __syncthreads();
    }
    if (t == 0) *flag = (s[0] > 8192) ? 1 : 0;  // 1 = inputs are bf16
}

// ---------- pack weight K x COLS into MFMA B-operand order ----------
template <int K, int COLS>
__global__ void k_packW(const void* __restrict__ src, unsigned short* __restrict__ dst,
                        const int* __restrict__ dflag) {
    constexpr int CT = COLS / 16;
    int i = blockIdx.x * 256 + threadIdx.x;
    if (i >= K * COLS) return;
    int j = i & 7;
    int lane = (i >> 3) & 63;
    int rest = i >> 9;
    int ct = rest % CT;
    int kt = rest / CT;
    int k = kt * 32 + (lane >> 4) * 8 + j;
    int c = ct * 16 + (lane & 15);
    int si = k * COLS + c;
    dst[i] = (*dflag) ? ((const unsigned short*)src)[si] : f2bf(((const float*)src)[si]);
}

// ---------- preprocessing: degree histogram, scan, counting sort ----------
__global__ void k_hist(const int* __restrict__ row, int* __restrict__ cnt, int E) {
    int e = blockIdx.x * 256 + threadIdx.x;
    if (e < E) {
        unsigned int r = (unsigned int)row[e];
        if (r >= NN) r = 0;
        atomicAdd(&cnt[r], 1);
    }
}

__global__ void k_scan_a(const int* __restrict__ cnt, int* __restrict__ bsum, int n) {
    __shared__ int s[256];
    int i = blockIdx.x * 256 + threadIdx.x;
    s[threadIdx.x] = (i < n) ? cnt[i] : 0;
    __syncthreads();
    for (int off = 128; off > 0; off >>= 1) {
        if (threadIdx.x < off) s[threadIdx.x] += s[threadIdx.x + off];
        __syncthreads();
    }
    if (threadIdx.x == 0) bsum[blockIdx.x] = s[0];
}

__global__ void k_scan_b(int* bsum, int nchunks) {
    __shared__ int s[512];
    int t = threadIdx.x;
    int v = (t < nchunks) ? bsum[t] : 0;
    s[t] = v;
    __syncthreads();
    for (int off = 1; off < 512; off <<= 1) {
        int x = (t >= off) ? s[t - off] : 0;
        __syncthreads();
        s[t] += x;
        __syncthreads();
    }
    if (t < nchunks) bsum[t] = s[t] - v;  // exclusive
}

__global__ void k_scan_c(const int* __restrict__ cnt, const int* __restrict__ bsum,
                         int* __restrict__ offs, int* __restrict__ cursor, int n) {
    __shared__ int s[256];
    int t = threadIdx.x;
    int i = blockIdx.x * 256 + t;
    int v = (i < n) ? cnt[i] : 0;
    s[t] = v;
    __syncthreads();
    for (int off = 1; off < 256; off <<= 1) {
        int x = (t >= off) ? s[t - off] : 0;
        __syncthreads();
        s[t] += x;
        __syncthreads();
    }
    if (i < n) {
        int ex = bsum[blockIdx.x] + s[t] - v;
        offs[i] = ex;
        cursor[i] = ex;
    }
}

__global__ void k_scatter(const int* __restrict__ row, const int* __restrict__ col,
                          int* __restrict__ cursor, int* __restrict__ colS, int E) {
    int e = blockIdx.x * 256 + threadIdx.x;
    if (e < E) {
        unsigned int r = (unsigned int)row[e];
        if (r >= NN) r = 0;
        unsigned int c = (unsigned int)col[e];
        if (c >= NN) c = 0;
        int p = atomicAdd(&cursor[r], 1);
        colS[p] = (int)c;
    }
}

__global__ void k_dinv(const int* __restrict__ cnt, float* __restrict__ dinv, int n) {
    int i = blockIdx.x * 256 + threadIdx.x;
    if (i < n) dinv[i] = rsqrtf((float)(cnt[i] + 1));  // +1 self loop
}

// ---------- MFMA GEMM: G[r][c] = dinv[r] * sum_k relu?(A[r][k]) * W[k][c]; G bf16 ----------
template <int K, int COLS, bool RELU, int AMODE>
__global__ __launch_bounds__(256) void k_gemm(const void* __restrict__ Av,
                                              const unsigned short* __restrict__ Wp,
                                              const float* __restrict__ dinv,
                                              unsigned short* __restrict__ G, int nrows,
                                              const int* __restrict__ dflag) {
    constexpr int CT = COLS / 16;
    constexpr int KT = K / 32;
    __shared__ unsigned short tile[4][16][136];

    int t = threadIdx.x;
    int wave = t >> 6, lane = t & 63;
    int quad = lane >> 4, m = lane & 15;
    int r0 = blockIdx.x * 64 + wave * 16;
    int arow = r0 + m;
    bool rowok = arow < nrows;
    bool abf = (AMODE == 0) || (*dflag != 0);

    const unsigned short* Ab = (const unsigned short*)Av;
    const float* Af = (const float*)Av;

    f32x4 acc[CT];
#pragma unroll
    for (int ct = 0; ct < CT; ct++) acc[ct] = (f32x4){0.f, 0.f, 0.f, 0.f};

    for (int kt = 0; kt < KT; kt++) {
        int kb = kt * 32 + quad * 8;
        bf16x8 afrag = (bf16x8)0;
        if (rowok) {
            if (abf) {
                afrag = *(const bf16x8*)(Ab + (size_t)arow * K + kb);
                if constexpr (RELU) {
#pragma unroll
                    for (int j = 0; j < 8; j++) {
                        unsigned short u = (unsigned short)afrag[j];
                        afrag[j] = (u & 0x8000u) ? (short)0 : (short)u;
                    }
                }
            } else {
                float4 f0 = *(const float4*)(Af + (size_t)arow * K + kb);
                float4 f1 = *(const float4*)(Af + (size_t)arow * K + kb + 4);
                afrag[0] = (short)f2bf(f0.x); afrag[1] = (short)f2bf(f0.y);
                afrag[2] = (short)f2bf(f0.z); afrag[3] = (short)f2bf(f0.w);
                afrag[4] = (short)f2bf(f1.x); afrag[5] = (short)f2bf(f1.y);
                afrag[6] = (short)f2bf(f1.z); afrag[7] = (short)f2bf(f1.w);
            }
        }
#pragma unroll
        for (int ct = 0; ct < CT; ct++) {
            bf16x8 bfrag = *(const bf16x8*)(Wp + (((size_t)kt * CT + ct) * 64 + lane) * 8);
            acc[ct] = __builtin_amdgcn_mfma_f32_16x16x32_bf16(afrag, bfrag, acc[ct], 0, 0, 0);
        }
    }

    float dv[4];
#pragma unroll
    for (int rg = 0; rg < 4; rg++) {
        int gr = r0 + quad * 4 + rg;
        dv[rg] = dinv[gr < nrows ? gr : 0];
    }
#pragma unroll
    for (int ct = 0; ct < CT; ct++) {
#pragma unroll
        for (int rg = 0; rg < 4; rg++)
            tile[wave][quad * 4 + rg][ct * 16 + m] = f2bf(acc[ct][rg] * dv[rg]);
    }
    int srow = lane >> 2;
    int grow = r0 + srow;
    if (grow < nrows) {
        constexpr int CH = COLS / 32;
#pragma unroll
        for (int j8 = 0; j8 < CH; j8++) {
            int c = (lane & 3) * 8 + j8 * 32;
            uint4 v = *(const uint4*)&tile[wave][srow][c];
            *(uint4*)(G + (size_t)grow * COLS + c) = v;
        }
    }
}

// ---------- aggregate: out[r] = relu?(dinv[r]*(g[r] + sum_{c in adj(r)} g[c])) ----------
template <int D, bool RELU, bool FINAL>
__global__ __launch_bounds__(256) void k_agg(const unsigned short* __restrict__ g,
                                             const int* __restrict__ colS,
                                             const int* __restrict__ offs,
                                             const int* __restrict__ cnt,
                                             const float* __restrict__ dinv,
                                             unsigned short* __restrict__ obf,
                                             void* __restrict__ oraw,
                                             const int* __restrict__ dflag, int n) {
    int lane = threadIdx.x & 63;
    int node = blockIdx.x * 4 + (threadIdx.x >> 6);
    if (node >= n) return;
    int start = offs[node];
    int deg = cnt[node];

    float a0 = 0.f, a1 = 0.f;
    if constexpr (D == 128) {
        unsigned int u = *(const unsigned int*)(g + (size_t)node * 128 + lane * 2);
        a0 = bf2f(u); a1 = bf2f(u >> 16);
    } else {
        a0 = bf2f(g[(size_t)node * 64 + lane]);
    }

    for (int base = 0; base < deg; base += 64) {
        int rem = deg - base;
        int nb = rem < 64 ? rem : 64;
        int cidx = 0;
        if (lane < nb) cidx = colS[start + base + lane];
        int j = 0;
        for (; j + 4 <= nb; j += 4) {
            int c0 = __shfl(cidx, j);
            int c1 = __shfl(cidx, j + 1);
            int c2 = __shfl(cidx, j + 2);
            int c3 = __shfl(cidx, j + 3);
            if constexpr (D == 128) {
                unsigned int u0 = *(const unsigned int*)(g + (size_t)c0 * 128 + lane * 2);
                unsigned int u1 = *(const unsigned int*)(g + (size_t)c1 * 128 + lane * 2);
                unsigned int u2 = *(const unsigned int*)(g + (size_t)c2 * 128 + lane * 2);
                unsigned int u3 = *(const unsigned int*)(g + (size_t)c3 * 128 + lane * 2);
                a0 += bf2f(u0); a1 += bf2f(u0 >> 16);
                a0 += bf2f(u1); a1 += bf2f(u1 >> 16);
                a0 += bf2f(u2); a1 += bf2f(u2 >> 16);
                a0 += bf2f(u3); a1 += bf2f(u3 >> 16);
            } else {
                unsigned short u0 = g[(size_t)c0 * 64 + lane];
                unsigned short u1 = g[(size_t)c1 * 64 + lane];
                unsigned short u2 = g[(size_t)c2 * 64 + lane];
                unsigned short u3 = g[(size_t)c3 * 64 + lane];
                a0 += bf2f(u0) + bf2f(u1) + bf2f(u2) + bf2f(u3);
            }
        }
        for (; j < nb; j++) {
            int cj = __shfl(cidx, j);
            if constexpr (D == 128) {
                unsigned int u = *(const unsigned int*)(g + (size_t)cj * 128 + lane * 2);
                a0 += bf2f(u); a1 += bf2f(u >> 16);
            } else {
                a0 += bf2f(g[(size_t)cj * 64 + lane]);
            }
        }
    }

    float s = dinv[node];
    a0 *= s; a1 *= s;
    if constexpr (RELU) { a0 = fmaxf(a0, 0.f); a1 = fmaxf(a1, 0.f); }

    if constexpr (D == 128) {
        *(unsigned int*)(obf + (size_t)node * 128 + lane * 2) =
            (unsigned int)f2bf(a0) | ((unsigned int)f2bf(a1) << 16);
    } else {
        obf[(size_t)node * 64 + lane] = f2bf(a0);
        if constexpr (FINAL) {
            if (*dflag) ((unsigned short*)oraw)[(size_t)node * 64 + lane] = f2bf(a0);
            else        ((float*)oraw)[(size_t)node * 64 + lane] = a0;
        }
    }
}

// ---------- column sums (vectorized bf16x8 loads + LDS reduce) ----------
template <int D>
__global__ __launch_bounds__(256) void k_colsum(const unsigned short* __restrict__ in,
                                                float* __restrict__ colsum, int n) {
    constexpr int CG = D / 8;
    constexpr int RPB = 256 / CG;
    __shared__ float red[RPB][D];
    int t = threadIdx.x;
    int cg = t % CG, r0 = t / CG;
    int c0 = cg * 8;
    float a[8];
#pragma unroll
    for (int i = 0; i < 8; i++) a[i] = 0.f;
    for (int r = blockIdx.x * RPB + r0; r < n; r += gridDim.x * RPB) {
        bf16x8 u = *(const bf16x8*)(in + (size_t)r * D + c0);
#pragma unroll
        for (int i = 0; i < 8; i++) a[i] += bf2f((unsigned short)u[i]);
    }
#pragma unroll
    for (int i = 0; i < 8; i++) red[r0][c0 + i] = a[i];
    __syncthreads();
    if (t < D) {
        float s = 0.f;
#pragma unroll
        for (int r = 0; r < RPB; r++) s += red[r][t];
        atomicAdd(&colsum[t], s);
    }
}

// ---------- MFMA covariance: part[b] = sum over this block's 32-row chunks of Hc^T Hc ----------
// Hc = bf16(h - mean), staged TRANSPOSED in LDS as packed (k,k+1) dwords with a rotation
// swizzle (slot = ((kp>>2 + c>>3)&3)*4 + (kp&3)) so ds_read_b128 frag loads stay 16B-aligned
// with <=4-way conflicts. B-fragments live in a constant-indexed array; A-fragments are NAMED
// registers loaded via runtime LDS addresses — NO dynamically-indexed register arrays
// (R5's frag[tr] was demoted to scratch = hidden global traffic, the 10x slowdown).
template <int D>
__global__ __launch_bounds__(256) void k_cov2(const unsigned short* __restrict__ in,
                                              const float* __restrict__ colsum,
                                              float* __restrict__ part, int n, int nblocks) {
    constexpr int CT = D / 16;               // col tiles: 8 (D=128) or 4 (D=64)
    constexpr int TPW = (D == 128) ? 2 : 1;  // row tiles per wave
    constexpr int CG = D / 8;                // c-groups per row
    __shared__ unsigned int lds32[D * 16];
    __shared__ float smean[D];

    int t = threadIdx.x;
    int wave = t >> 6, lane = t & 63;
    int quad = lane >> 4, m = lane & 15;

    if (t < D) smean[t] = colsum[t] * (1.0f / (float)NN);
    __syncthreads();

    f32x4 accA[CT], accB[CT];
#pragma unroll
    for (int tc = 0; tc < CT; tc++) {
        accA[tc] = (f32x4){0.f, 0.f, 0.f, 0.f};
        accB[tc] = (f32x4){0.f, 0.f, 0.f, 0.f};
    }

    // loop-invariant staging params (hoisted): per-thread column block + swizzle slot + means
    bool stager = (t < 16 * CG);
    int kp = stager ? (t / CG) : 0;
    int c0 = stager ? ((t % CG) * 8) : 0;
    int slot = (((kp >> 2) + (c0 >> 3)) & 3) * 4 + (kp & 3);
    float sm[8];
#pragma unroll
    for (int i = 0; i < 8; i++) sm[i] = smean[c0 + i];

    // A-frag LDS addresses (runtime address arithmetic — fine; not register indexing)
    int ca0 = (wave * TPW) * 16 + m;
    int ga0 = (quad + (ca0 >> 3)) & 3;
    int ca1 = ca0 + 16;
    int ga1 = (quad + (ca1 >> 3)) & 3;

    int nchunks = (n + 31) / 32;
    for (int ch = blockIdx.x; ch < nchunks; ch += nblocks) {
        int k0 = ch * 32;
        if (stager) {
            int k = k0 + 2 * kp;
            bf16x8 u0 = (bf16x8)0, u1 = (bf16x8)0;
            bool ok0 = (k < n), ok1 = (k + 1 < n);
            if (ok0) u0 = *(const bf16x8*)(in + (size_t)k * D + c0);
            if (ok1) u1 = *(const bf16x8*)(in + (size_t)(k + 1) * D + c0);
#pragma unroll
            for (int i = 0; i < 8; i++) {
                float a = ok0 ? (bf2f((unsigned short)u0[i]) - sm[i]) : 0.f;
                float b = ok1 ? (bf2f((unsigned short)u1[i]) - sm[i]) : 0.f;
                lds32[(c0 + i) * 16 + slot] = (unsigned int)f2bf(a) | ((unsigned int)f2bf(b) << 16);
            }
        }
        __syncthreads();

        bf16x8 bfr[CT];  // constant-indexed only
#pragma unroll
        for (int tc = 0; tc < CT; tc++) {
            int c = tc * 16 + m;
            int grp = (quad + (c >> 3)) & 3;
            bfr[tc] = *(const bf16x8*)&lds32[c * 16 + grp * 4];
        }
        bf16x8 afr0 = *(const bf16x8*)&lds32[ca0 * 16 + ga0 * 4];
#pragma unroll
        for (int tc = 0; tc < CT; tc++)
            accA[tc] = __builtin_amdgcn_mfma_f32_16x16x32_bf16(afr0, bfr[tc], accA[tc], 0, 0, 0);
        if constexpr (TPW == 2) {
            bf16x8 afr1 = *(const bf16x8*)&lds32[ca1 * 16 + ga1 * 4];
#pragma unroll
            for (int tc = 0; tc < CT; tc++)
                accB[tc] = __builtin_amdgcn_mfma_f32_16x16x32_bf16(afr1, bfr[tc], accB[tc], 0, 0, 0);
        }
        __syncthreads();
    }

    float* p = part + (size_t)blockIdx.x * D * D;
    int tr0 = wave * TPW;
#pragma unroll
    for (int tc = 0; tc < CT; tc++) {
#pragma unroll
        for (int rg = 0; rg < 4; rg++) {
            int cj = tc * 16 + m;
            p[(tr0 * 16 + quad * 4 + rg) * D + cj] = accA[tc][rg];
            if constexpr (TPW == 2)
                p[((tr0 + 1) * 16 + quad * 4 + rg) * D + cj] = accB[tc][rg];
        }
    }
}

template <int D>
__global__ void k_covred(const float* __restrict__ part, float* __restrict__ cov, int nblocks) {
    int idx = blockIdx.x * 256 + threadIdx.x;
    if (idx >= D * D) return;
    float s = 0.f;
    for (int b = 0; b < nblocks; b++) s += part[(size_t)b * D * D + idx];
    cov[idx] = s;
}

template <int D>
__global__ __launch_bounds__(256) void k_fin(const float* __restrict__ cov,
                                             void* __restrict__ out, long long idx,
                                             const int* __restrict__ dflag) {
    __shared__ float sd[D];
    __shared__ float red[256];
    int t = threadIdx.x;
    if (t < D) sd[t] = sqrtf(fmaxf(cov[t * D + t], 1e-12f));
    __syncthreads();
    float s = 0.f;
    for (int i2 = t; i2 < D * D; i2 += 256) {
        int i = i2 / D, j = i2 % D;
        if (j > i) s += fabsf(cov[i2] / (sd[i] * sd[j]));
    }
    red[t] = s;
    __syncthreads();
    for (int off = 128; off > 0; off >>= 1) {
        if (t < off) red[t] += red[t + off];
        __syncthreads();
    }
    if (t == 0) {
        float v = red[0] / (float)(D * (D - 1) / 2);
        if (*dflag) ((unsigned short*)out)[idx] = f2bf(v);
        else        ((float*)out)[idx] = v;
    }
}

// ---------- launch ----------
extern "C" void kernel_launch(void* const* d_in, const int* in_sizes, int n_in,
                              void* d_out, int out_size, void* d_ws, size_t ws_size,
                              hipStream_t stream) {
    const void* x = d_in[0];
    const int* ei = (const int*)d_in[1];

    int E = in_sizes[1] / 2;
    const int* row = ei;
    const int* col = ei + E;

    char* w = (char*)d_ws;
    auto carve = [&](size_t bytes) {
        void* p = (void*)w;
        w += (bytes + 255) & ~(size_t)255;
        return p;
    };
    int* cnt = (int*)carve((size_t)NN * 4);
    int* offs = (int*)carve((size_t)NN * 4);
    int* cursor = (int*)carve((size_t)NN * 4);
    int* bsum = (int*)carve(512 * 4);
    int* colS = (int*)carve((size_t)E * 4);
    float* dinv = (float*)carve((size_t)NN * 4);
    float* colsum = (float*)carve(HD * 4);
    float* covs = (float*)carve(HD * HD * 4);
    int* dflag = (int*)carve(256);
    unsigned short* wc = (unsigned short*)carve((size_t)(FIN * HD + HD * HD * 2 + HD * CD) * 2);
    unsigned short* bufA = (unsigned short*)carve((size_t)NN * HD * 2);
    unsigned short* bufB = (unsigned short*)carve((size_t)NN * HD * 2);

    unsigned short* wc0 = wc;              // 256x128 packed
    unsigned short* wc1 = wc + FIN * HD;   // 128x128 packed
    unsigned short* wc2 = wc1 + HD * HD;   // 128x128 packed
    unsigned short* wc3 = wc2 + HD * HD;   // 128x64 packed

    // cov partials alias bufB (dead during both corr computations)
    float* part = (float*)bufB;
    const int NBC = 250;  // partials: 250 * 64KB = 16MB <= bufB 25.6MB

    int nchunks = (NN + 255) / 256;
    int eblocks = (E + 255) / 256;
    int GB = (NN + 63) / 64;

    // dtype detection + weight packing
    k_detect<<<1, 256, 0, stream>>>((const unsigned short*)x, dflag);
    k_packW<256, 128><<<(FIN * HD) / 256, 256, 0, stream>>>(d_in[2], wc0, dflag);
    k_packW<128, 128><<<(HD * HD) / 256, 256, 0, stream>>>(d_in[3], wc1, dflag);
    k_packW<128, 128><<<(HD * HD) / 256, 256, 0, stream>>>(d_in[4], wc2, dflag);
    k_packW<128, 64><<<(HD * CD) / 256, 256, 0, stream>>>(d_in[5], wc3, dflag);

    // preprocessing (CSR by destination)
    hipMemsetAsync(cnt, 0, (size_t)NN * 4, stream);
    k_hist<<<eblocks, 256, 0, stream>>>(row, cnt, E);
    k_scan_a<<<nchunks, 256, 0, stream>>>(cnt, bsum, NN);
    k_scan_b<<<1, 512, 0, stream>>>(bsum, nchunks);
    k_scan_c<<<nchunks, 256, 0, stream>>>(cnt, bsum, offs, cursor, NN);
    k_scatter<<<eblocks, 256, 0, stream>>>(row, col, cursor, colS, E);
    k_dinv<<<nchunks, 256, 0, stream>>>(cnt, dinv, NN);

    // layer 0
    k_gemm<256, 128, false, 2><<<GB, 256, 0, stream>>>(x, wc0, dinv, bufB, NN, dflag);
    k_agg<128, true, false><<<NN / 4, 256, 0, stream>>>(bufB, colS, offs, cnt, dinv, bufA, nullptr, dflag, NN);
    // layer 1
    k_gemm<128, 128, false, 0><<<GB, 256, 0, stream>>>(bufA, wc1, dinv, bufB, NN, dflag);
    k_agg<128, true, false><<<NN / 4, 256, 0, stream>>>(bufB, colS, offs, cnt, dinv, bufA, nullptr, dflag, NN);
    // layer 2 (pre-ReLU kept in bufA for corr_2)
    k_gemm<128, 128, false, 0><<<GB, 256, 0, stream>>>(bufA, wc2, dinv, bufB, NN, dflag);
    k_agg<128, false, false><<<NN / 4, 256, 0, stream>>>(bufB, colS, offs, cnt, dinv, bufA, nullptr, dflag, NN);

    // corr_2 on bufA (bf16, D=128): colsum -> MFMA cov partials (in bufB) -> reduce -> fin
    hipMemsetAsync(colsum, 0, HD * 4, stream);
    k_colsum<128><<<64, 256, 0, stream>>>(bufA, colsum, NN);
    k_cov2<128><<<NBC, 256, 0, stream>>>(bufA, colsum, part, NN, NBC);
    k_covred<128><<<(HD * HD + 255) / 256, 256, 0, stream>>>(part, covs, NBC);
    k_fin<128><<<1, 256, 0, stream>>>(covs, d_out, (long long)NN * CD, dflag);

    // layer 3: relu(bufA) @ W3 -> bufB ; aggregate -> d_out (+ bf16 mirror in bufA)
    k_gemm<128, 64, true, 0><<<GB, 256, 0, stream>>>(bufA, wc3, dinv, bufB, NN, dflag);
    k_agg<64, false, true><<<NN / 4, 256, 0, stream>>>(bufB, colS, offs, cnt, dinv, bufA, d_out, dflag, NN);

    // corr on final output (bf16 mirror in bufA, D=64)
    hipMemsetAsync(colsum, 0, HD * 4, stream);
    k_colsum<64><<<64, 256, 0, stream>>>(bufA, colsum, NN);
    k_cov2<64><<<NBC, 256, 0, stream>>>(bufA, colsum, part, NN, NBC);
    k_covred<64><<<(CD * CD + 255) / 256, 256, 0, stream>>>(part, covs, NBC);
    k_fin<64><<<1, 256, 0, stream>>>(covs, d_out, (long long)NN * CD + 1, dflag);
}

// Round 7
// 942.853 us; speedup vs baseline: 1.8674x; 1.0101x over previous
//
#include <hip/hip_runtime.h>

#define NN 100000
#define FIN 256
#define HD 128
#define CD 64

typedef __attribute__((ext_vector_type(8))) short bf16x8;
typedef __attribute__((ext_vector_type(4))) float f32x4;

// ---------- bf16 helpers ----------
__device__ __forceinline__ float bf2f(unsigned int u16) {
    union { unsigned int u; float f; } v;
    v.u = (u16 & 0xffffu) << 16;
    return v.f;
}
__device__ __forceinline__ unsigned short f2bf(float f) {
    union { float f; unsigned int u; } v;
    v.f = f;
    unsigned int u = v.u + 0x7fffu + ((v.u >> 16) & 1u);  // RNE
    return (unsigned short)(u >> 16);
}

// ---------- dtype detection (inputs bf16 vs fp32; measured R3: fp32) ----------
__global__ void k_detect(const unsigned short* __restrict__ x, int* __restrict__ flag) {
    __shared__ int s[256];
    int t = threadIdx.x;
    int c = 0;
    for (int i = t; i < 16384; i += 256) {
        unsigned int e = (x[2 * i] >> 7) & 0xFF;
        c += (e >= 112 && e <= 134) ? 1 : 0;
    }
    s[t] = c;
    __syncthreads();
    for (int off = 128; off > 0; off >>= 1) {
        if (t < off) s[t] += s[t + off];
        __syncthreads();
    }
    if (t == 0) *flag = (s[0] > 8192) ? 1 : 0;  // 1 = inputs are bf16
}

// ---------- pack weight K x COLS into MFMA B-operand order ----------
template <int K, int COLS>
__global__ void k_packW(const void* __restrict__ src, unsigned short* __restrict__ dst,
                        const int* __restrict__ dflag) {
    constexpr int CT = COLS / 16;
    int i = blockIdx.x * 256 + threadIdx.x;
    if (i >= K * COLS) return;
    int j = i & 7;
    int lane = (i >> 3) & 63;
    int rest = i >> 9;
    int ct = rest % CT;
    int kt = rest / CT;
    int k = kt * 32 + (lane >> 4) * 8 + j;
    int c = ct * 16 + (lane & 15);
    int si = k * COLS + c;
    dst[i] = (*dflag) ? ((const unsigned short*)src)[si] : f2bf(((const float*)src)[si]);
}

// ---------- preprocessing: degree histogram, scan, counting sort ----------
__global__ void k_hist(const int* __restrict__ row, int* __restrict__ cnt, int E) {
    int e = blockIdx.x * 256 + threadIdx.x;
    if (e < E) {
        unsigned int r = (unsigned int)row[e];
        if (r >= NN) r = 0;
        atomicAdd(&cnt[r], 1);
    }
}

__global__ void k_scan_a(const int* __restrict__ cnt, int* __restrict__ bsum, int n) {
    __shared__ int s[256];
    int i = blockIdx.x * 256 + threadIdx.x;
    s[threadIdx.x] = (i < n) ? cnt[i] : 0;
    __syncthreads();
    for (int off = 128; off > 0; off >>= 1) {
        if (threadIdx.x < off) s[threadIdx.x] += s[threadIdx.x + off];
        __syncthreads();
    }
    if (threadIdx.x == 0) bsum[blockIdx.x] = s[0];
}

__global__ void k_scan_b(int* bsum, int nchunks) {
    __shared__ int s[512];
    int t = threadIdx.x;
    int v = (t < nchunks) ? bsum[t] : 0;
    s[t] = v;
    __syncthreads();
    for (int off = 1; off < 512; off <<= 1) {
        int x = (t >= off) ? s[t - off] : 0;
        __syncthreads();
        s[t] += x;
        __syncthreads();
    }
    if (t < nchunks) bsum[t] = s[t] - v;  // exclusive
}

__global__ void k_scan_c(const int* __restrict__ cnt, const int* __restrict__ bsum,
                         int* __restrict__ offs, int* __restrict__ cursor, int n) {
    __shared__ int s[256];
    int t = threadIdx.x;
    int i = blockIdx.x * 256 + t;
    int v = (i < n) ? cnt[i] : 0;
    s[t] = v;
    __syncthreads();
    for (int off = 1; off < 256; off <<= 1) {
        int x = (t >= off) ? s[t - off] : 0;
        __syncthreads();
        s[t] += x;
        __syncthreads();
    }
    if (i < n) {
        int ex = bsum[blockIdx.x] + s[t] - v;
        offs[i] = ex;
        cursor[i] = ex;
    }
}

// Windowed scatter: only edges with lo <= row < hi are placed. Running P sequential
// passes keeps each pass's colS writes inside a (6.4/P) MB window -> lines coalesce
// in L2 before writeback (R6: unwindowed random 4B stores cost 106 MB of HBM writes).
__global__ void k_scatter(const int* __restrict__ row, const int* __restrict__ col,
                          int* __restrict__ cursor, int* __restrict__ colS, int E,
                          int lo, int hi) {
    int e = blockIdx.x * 256 + threadIdx.x;
    if (e < E) {
        unsigned int r = (unsigned int)row[e];
        if (r >= NN) r = 0;
        if ((int)r >= lo && (int)r < hi) {
            unsigned int c = (unsigned int)col[e];
            if (c >= NN) c = 0;
            int p = atomicAdd(&cursor[r], 1);
            colS[p] = (int)c;
        }
    }
}

__global__ void k_dinv(const int* __restrict__ cnt, float* __restrict__ dinv, int n) {
    int i = blockIdx.x * 256 + threadIdx.x;
    if (i < n) dinv[i] = rsqrtf((float)(cnt[i] + 1));  // +1 self loop
}

// ---------- MFMA GEMM: G[r][c] = dinv[r] * sum_k relu?(A[r][k]) * W[k][c]; G bf16 ----------
template <int K, int COLS, bool RELU, int AMODE>
__global__ __launch_bounds__(256) void k_gemm(const void* __restrict__ Av,
                                              const unsigned short* __restrict__ Wp,
                                              const float* __restrict__ dinv,
                                              unsigned short* __restrict__ G, int nrows,
                                              const int* __restrict__ dflag) {
    constexpr int CT = COLS / 16;
    constexpr int KT = K / 32;
    __shared__ unsigned short tile[4][16][136];

    int t = threadIdx.x;
    int wave = t >> 6, lane = t & 63;
    int quad = lane >> 4, m = lane & 15;
    int r0 = blockIdx.x * 64 + wave * 16;
    int arow = r0 + m;
    bool rowok = arow < nrows;
    bool abf = (AMODE == 0) || (*dflag != 0);

    const unsigned short* Ab = (const unsigned short*)Av;
    const float* Af = (const float*)Av;

    f32x4 acc[CT];
#pragma unroll
    for (int ct = 0; ct < CT; ct++) acc[ct] = (f32x4){0.f, 0.f, 0.f, 0.f};

    for (int kt = 0; kt < KT; kt++) {
        int kb = kt * 32 + quad * 8;
        bf16x8 afrag = (bf16x8)0;
        if (rowok) {
            if (abf) {
                afrag = *(const bf16x8*)(Ab + (size_t)arow * K + kb);
                if constexpr (RELU) {
#pragma unroll
                    for (int j = 0; j < 8; j++) {
                        unsigned short u = (unsigned short)afrag[j];
                        afrag[j] = (u & 0x8000u) ? (short)0 : (short)u;
                    }
                }
            } else {
                float4 f0 = *(const float4*)(Af + (size_t)arow * K + kb);
                float4 f1 = *(const float4*)(Af + (size_t)arow * K + kb + 4);
                afrag[0] = (short)f2bf(f0.x); afrag[1] = (short)f2bf(f0.y);
                afrag[2] = (short)f2bf(f0.z); afrag[3] = (short)f2bf(f0.w);
                afrag[4] = (short)f2bf(f1.x); afrag[5] = (short)f2bf(f1.y);
                afrag[6] = (short)f2bf(f1.z); afrag[7] = (short)f2bf(f1.w);
            }
        }
#pragma unroll
        for (int ct = 0; ct < CT; ct++) {
            bf16x8 bfrag = *(const bf16x8*)(Wp + (((size_t)kt * CT + ct) * 64 + lane) * 8);
            acc[ct] = __builtin_amdgcn_mfma_f32_16x16x32_bf16(afrag, bfrag, acc[ct], 0, 0, 0);
        }
    }

    float dv[4];
#pragma unroll
    for (int rg = 0; rg < 4; rg++) {
        int gr = r0 + quad * 4 + rg;
        dv[rg] = dinv[gr < nrows ? gr : 0];
    }
#pragma unroll
    for (int ct = 0; ct < CT; ct++) {
#pragma unroll
        for (int rg = 0; rg < 4; rg++)
            tile[wave][quad * 4 + rg][ct * 16 + m] = f2bf(acc[ct][rg] * dv[rg]);
    }
    int srow = lane >> 2;
    int grow = r0 + srow;
    if (grow < nrows) {
        constexpr int CH = COLS / 32;
#pragma unroll
        for (int j8 = 0; j8 < CH; j8++) {
            int c = (lane & 3) * 8 + j8 * 32;
            uint4 v = *(const uint4*)&tile[wave][srow][c];
            *(uint4*)(G + (size_t)grow * COLS + c) = v;
        }
    }
}

// ---------- aggregate: out[r] = relu?(dinv[r]*(g[r] + sum_{c in adj(r)} g[c])) ----------
// 8-deep load pipelining (named registers only; dynamic register indexing = scratch, R5).
template <int D, bool RELU, bool FINAL>
__global__ __launch_bounds__(256) void k_agg(const unsigned short* __restrict__ g,
                                             const int* __restrict__ colS,
                                             const int* __restrict__ offs,
                                             const int* __restrict__ cnt,
                                             const float* __restrict__ dinv,
                                             unsigned short* __restrict__ obf,
                                             void* __restrict__ oraw,
                                             const int* __restrict__ dflag, int n) {
    int lane = threadIdx.x & 63;
    int node = blockIdx.x * 4 + (threadIdx.x >> 6);
    if (node >= n) return;
    int start = offs[node];
    int deg = cnt[node];

    float a0 = 0.f, a1 = 0.f;
    if constexpr (D == 128) {
        unsigned int u = *(const unsigned int*)(g + (size_t)node * 128 + lane * 2);
        a0 = bf2f(u); a1 = bf2f(u >> 16);
    } else {
        a0 = bf2f(g[(size_t)node * 64 + lane]);
    }

    for (int base = 0; base < deg; base += 64) {
        int rem = deg - base;
        int nb = rem < 64 ? rem : 64;
        int cidx = 0;
        if (lane < nb) cidx = colS[start + base + lane];
        int j = 0;
        for (; j + 8 <= nb; j += 8) {
            int c0 = __shfl(cidx, j);
            int c1 = __shfl(cidx, j + 1);
            int c2 = __shfl(cidx, j + 2);
            int c3 = __shfl(cidx, j + 3);
            int c4 = __shfl(cidx, j + 4);
            int c5 = __shfl(cidx, j + 5);
            int c6 = __shfl(cidx, j + 6);
            int c7 = __shfl(cidx, j + 7);
            if constexpr (D == 128) {
                unsigned int u0 = *(const unsigned int*)(g + (size_t)c0 * 128 + lane * 2);
                unsigned int u1 = *(const unsigned int*)(g + (size_t)c1 * 128 + lane * 2);
                unsigned int u2 = *(const unsigned int*)(g + (size_t)c2 * 128 + lane * 2);
                unsigned int u3 = *(const unsigned int*)(g + (size_t)c3 * 128 + lane * 2);
                unsigned int u4 = *(const unsigned int*)(g + (size_t)c4 * 128 + lane * 2);
                unsigned int u5 = *(const unsigned int*)(g + (size_t)c5 * 128 + lane * 2);
                unsigned int u6 = *(const unsigned int*)(g + (size_t)c6 * 128 + lane * 2);
                unsigned int u7 = *(const unsigned int*)(g + (size_t)c7 * 128 + lane * 2);
                a0 += bf2f(u0); a1 += bf2f(u0 >> 16);
                a0 += bf2f(u1); a1 += bf2f(u1 >> 16);
                a0 += bf2f(u2); a1 += bf2f(u2 >> 16);
                a0 += bf2f(u3); a1 += bf2f(u3 >> 16);
                a0 += bf2f(u4); a1 += bf2f(u4 >> 16);
                a0 += bf2f(u5); a1 += bf2f(u5 >> 16);
                a0 += bf2f(u6); a1 += bf2f(u6 >> 16);
                a0 += bf2f(u7); a1 += bf2f(u7 >> 16);
            } else {
                unsigned short u0 = g[(size_t)c0 * 64 + lane];
                unsigned short u1 = g[(size_t)c1 * 64 + lane];
                unsigned short u2 = g[(size_t)c2 * 64 + lane];
                unsigned short u3 = g[(size_t)c3 * 64 + lane];
                unsigned short u4 = g[(size_t)c4 * 64 + lane];
                unsigned short u5 = g[(size_t)c5 * 64 + lane];
                unsigned short u6 = g[(size_t)c6 * 64 + lane];
                unsigned short u7 = g[(size_t)c7 * 64 + lane];
                a0 += bf2f(u0) + bf2f(u1) + bf2f(u2) + bf2f(u3);
                a0 += bf2f(u4) + bf2f(u5) + bf2f(u6) + bf2f(u7);
            }
        }
        for (; j < nb; j++) {
            int cj = __shfl(cidx, j);
            if constexpr (D == 128) {
                unsigned int u = *(const unsigned int*)(g + (size_t)cj * 128 + lane * 2);
                a0 += bf2f(u); a1 += bf2f(u >> 16);
            } else {
                a0 += bf2f(g[(size_t)cj * 64 + lane]);
            }
        }
    }

    float s = dinv[node];
    a0 *= s; a1 *= s;
    if constexpr (RELU) { a0 = fmaxf(a0, 0.f); a1 = fmaxf(a1, 0.f); }

    if constexpr (D == 128) {
        *(unsigned int*)(obf + (size_t)node * 128 + lane * 2) =
            (unsigned int)f2bf(a0) | ((unsigned int)f2bf(a1) << 16);
    } else {
        obf[(size_t)node * 64 + lane] = f2bf(a0);
        if constexpr (FINAL) {
            if (*dflag) ((unsigned short*)oraw)[(size_t)node * 64 + lane] = f2bf(a0);
            else        ((float*)oraw)[(size_t)node * 64 + lane] = a0;
        }
    }
}

// ---------- column sums (vectorized bf16x8 loads + LDS reduce) ----------
template <int D>
__global__ __launch_bounds__(256) void k_colsum(const unsigned short* __restrict__ in,
                                                float* __restrict__ colsum, int n) {
    constexpr int CG = D / 8;
    constexpr int RPB = 256 / CG;
    __shared__ float red[RPB][D];
    int t = threadIdx.x;
    int cg = t % CG, r0 = t / CG;
    int c0 = cg * 8;
    float a[8];
#pragma unroll
    for (int i = 0; i < 8; i++) a[i] = 0.f;
    for (int r = blockIdx.x * RPB + r0; r < n; r += gridDim.x * RPB) {
        bf16x8 u = *(const bf16x8*)(in + (size_t)r * D + c0);
#pragma unroll
        for (int i = 0; i < 8; i++) a[i] += bf2f((unsigned short)u[i]);
    }
#pragma unroll
    for (int i = 0; i < 8; i++) red[r0][c0 + i] = a[i];
    __syncthreads();
    if (t < D) {
        float s = 0.f;
#pragma unroll
        for (int r = 0; r < RPB; r++) s += red[r][t];
        atomicAdd(&colsum[t], s);
    }
}

// ---------- MFMA covariance (see R6 notes: no dynamic register indexing) ----------
template <int D>
__global__ __launch_bounds__(256) void k_cov2(const unsigned short* __restrict__ in,
                                              const float* __restrict__ colsum,
                                              float* __restrict__ part, int n, int nblocks) {
    constexpr int CT = D / 16;
    constexpr int TPW = (D == 128) ? 2 : 1;
    constexpr int CG = D / 8;
    __shared__ unsigned int lds32[D * 16];
    __shared__ float smean[D];

    int t = threadIdx.x;
    int wave = t >> 6, lane = t & 63;
    int quad = lane >> 4, m = lane & 15;

    if (t < D) smean[t] = colsum[t] * (1.0f / (float)NN);
    __syncthreads();

    f32x4 accA[CT], accB[CT];
#pragma unroll
    for (int tc = 0; tc < CT; tc++) {
        accA[tc] = (f32x4){0.f, 0.f, 0.f, 0.f};
        accB[tc] = (f32x4){0.f, 0.f, 0.f, 0.f};
    }

    bool stager = (t < 16 * CG);
    int kp = stager ? (t / CG) : 0;
    int c0 = stager ? ((t % CG) * 8) : 0;
    int slot = (((kp >> 2) + (c0 >> 3)) & 3) * 4 + (kp & 3);
    float sm[8];
#pragma unroll
    for (int i = 0; i < 8; i++) sm[i] = smean[c0 + i];

    int ca0 = (wave * TPW) * 16 + m;
    int ga0 = (quad + (ca0 >> 3)) & 3;
    int ca1 = ca0 + 16;
    int ga1 = (quad + (ca1 >> 3)) & 3;

    int nchunks = (n + 31) / 32;
    for (int ch = blockIdx.x; ch < nchunks; ch += nblocks) {
        int k0 = ch * 32;
        if (stager) {
            int k = k0 + 2 * kp;
            bf16x8 u0 = (bf16x8)0, u1 = (bf16x8)0;
            bool ok0 = (k < n), ok1 = (k + 1 < n);
            if (ok0) u0 = *(const bf16x8*)(in + (size_t)k * D + c0);
            if (ok1) u1 = *(const bf16x8*)(in + (size_t)(k + 1) * D + c0);
#pragma unroll
            for (int i = 0; i < 8; i++) {
                float a = ok0 ? (bf2f((unsigned short)u0[i]) - sm[i]) : 0.f;
                float b = ok1 ? (bf2f((unsigned short)u1[i]) - sm[i]) : 0.f;
                lds32[(c0 + i) * 16 + slot] = (unsigned int)f2bf(a) | ((unsigned int)f2bf(b) << 16);
            }
        }
        __syncthreads();

        bf16x8 bfr[CT];
#pragma unroll
        for (int tc = 0; tc < CT; tc++) {
            int c = tc * 16 + m;
            int grp = (quad + (c >> 3)) & 3;
            bfr[tc] = *(const bf16x8*)&lds32[c * 16 + grp * 4];
        }
        bf16x8 afr0 = *(const bf16x8*)&lds32[ca0 * 16 + ga0 * 4];
#pragma unroll
        for (int tc = 0; tc < CT; tc++)
            accA[tc] = __builtin_amdgcn_mfma_f32_16x16x32_bf16(afr0, bfr[tc], accA[tc], 0, 0, 0);
        if constexpr (TPW == 2) {
            bf16x8 afr1 = *(const bf16x8*)&lds32[ca1 * 16 + ga1 * 4];
#pragma unroll
            for (int tc = 0; tc < CT; tc++)
                accB[tc] = __builtin_amdgcn_mfma_f32_16x16x32_bf16(afr1, bfr[tc], accB[tc], 0, 0, 0);
        }
        __syncthreads();
    }

    float* p = part + (size_t)blockIdx.x * D * D;
    int tr0 = wave * TPW;
#pragma unroll
    for (int tc = 0; tc < CT; tc++) {
#pragma unroll
        for (int rg = 0; rg < 4; rg++) {
            int cj = tc * 16 + m;
            p[(tr0 * 16 + quad * 4 + rg) * D + cj] = accA[tc][rg];
            if constexpr (TPW == 2)
                p[((tr0 + 1) * 16 + quad * 4 + rg) * D + cj] = accB[tc][rg];
        }
    }
}

template <int D>
__global__ void k_covred(const float* __restrict__ part, float* __restrict__ cov, int nblocks) {
    int idx = blockIdx.x * 256 + threadIdx.x;
    if (idx >= D * D) return;
    float s = 0.f;
    for (int b = 0; b < nblocks; b++) s += part[(size_t)b * D * D + idx];
    cov[idx] = s;
}

template <int D>
__global__ __launch_bounds__(256) void k_fin(const float* __restrict__ cov,
                                             void* __restrict__ out, long long idx,
                                             const int* __restrict__ dflag) {
    __shared__ float sd[D];
    __shared__ float red[256];
    int t = threadIdx.x;
    if (t < D) sd[t] = sqrtf(fmaxf(cov[t * D + t], 1e-12f));
    __syncthreads();
    float s = 0.f;
    for (int i2 = t; i2 < D * D; i2 += 256) {
        int i = i2 / D, j = i2 % D;
        if (j > i) s += fabsf(cov[i2] / (sd[i] * sd[j]));
    }
    red[t] = s;
    __syncthreads();
    for (int off = 128; off > 0; off >>= 1) {
        if (t < off) red[t] += red[t + off];
        __syncthreads();
    }
    if (t == 0) {
        float v = red[0] / (float)(D * (D - 1) / 2);
        if (*dflag) ((unsigned short*)out)[idx] = f2bf(v);
        else        ((float*)out)[idx] = v;
    }
}

// ---------- launch ----------
extern "C" void kernel_launch(void* const* d_in, const int* in_sizes, int n_in,
                              void* d_out, int out_size, void* d_ws, size_t ws_size,
                              hipStream_t stream) {
    const void* x = d_in[0];
    const int* ei = (const int*)d_in[1];

    int E = in_sizes[1] / 2;
    const int* row = ei;
    const int* col = ei + E;

    char* w = (char*)d_ws;
    auto carve = [&](size_t bytes) {
        void* p = (void*)w;
        w += (bytes + 255) & ~(size_t)255;
        return p;
    };
    int* cnt = (int*)carve((size_t)NN * 4);
    int* offs = (int*)carve((size_t)NN * 4);
    int* cursor = (int*)carve((size_t)NN * 4);
    int* bsum = (int*)carve(512 * 4);
    int* colS = (int*)carve((size_t)E * 4);
    float* dinv = (float*)carve((size_t)NN * 4);
    float* colsum = (float*)carve(HD * 4);
    float* covs = (float*)carve(HD * HD * 4);
    int* dflag = (int*)carve(256);
    unsigned short* wc = (unsigned short*)carve((size_t)(FIN * HD + HD * HD * 2 + HD * CD) * 2);
    unsigned short* bufA = (unsigned short*)carve((size_t)NN * HD * 2);
    unsigned short* bufB = (unsigned short*)carve((size_t)NN * HD * 2);

    unsigned short* wc0 = wc;              // 256x128 packed
    unsigned short* wc1 = wc + FIN * HD;   // 128x128 packed
    unsigned short* wc2 = wc1 + HD * HD;   // 128x128 packed
    unsigned short* wc3 = wc2 + HD * HD;   // 128x64 packed

    float* part = (float*)bufB;  // cov partials alias bufB (dead during corr)
    const int NBC = 250;

    int nchunks = (NN + 255) / 256;
    int eblocks = (E + 255) / 256;
    int GB = (NN + 63) / 64;

    // dtype detection + weight packing
    k_detect<<<1, 256, 0, stream>>>((const unsigned short*)x, dflag);
    k_packW<256, 128><<<(FIN * HD) / 256, 256, 0, stream>>>(d_in[2], wc0, dflag);
    k_packW<128, 128><<<(HD * HD) / 256, 256, 0, stream>>>(d_in[3], wc1, dflag);
    k_packW<128, 128><<<(HD * HD) / 256, 256, 0, stream>>>(d_in[4], wc2, dflag);
    k_packW<128, 64><<<(HD * CD) / 256, 256, 0, stream>>>(d_in[5], wc3, dflag);

    // preprocessing (CSR by destination)
    hipMemsetAsync(cnt, 0, (size_t)NN * 4, stream);
    k_hist<<<eblocks, 256, 0, stream>>>(row, cnt, E);
    k_scan_a<<<nchunks, 256, 0, stream>>>(cnt, bsum, NN);
    k_scan_b<<<1, 512, 0, stream>>>(bsum, nchunks);
    k_scan_c<<<nchunks, 256, 0, stream>>>(cnt, bsum, offs, cursor, NN);
    // windowed scatter: 4 sequential passes, each writing a ~1.6MB colS window (L2-coalesced)
    k_scatter<<<eblocks, 256, 0, stream>>>(row, col, cursor, colS, E, 0, 25000);
    k_scatter<<<eblocks, 256, 0, stream>>>(row, col, cursor, colS, E, 25000, 50000);
    k_scatter<<<eblocks, 256, 0, stream>>>(row, col, cursor, colS, E, 50000, 75000);
    k_scatter<<<eblocks, 256, 0, stream>>>(row, col, cursor, colS, E, 75000, NN);
    k_dinv<<<nchunks, 256, 0, stream>>>(cnt, dinv, NN);

    // layer 0
    k_gemm<256, 128, false, 2><<<GB, 256, 0, stream>>>(x, wc0, dinv, bufB, NN, dflag);
    k_agg<128, true, false><<<NN / 4, 256, 0, stream>>>(bufB, colS, offs, cnt, dinv, bufA, nullptr, dflag, NN);
    // layer 1
    k_gemm<128, 128, false, 0><<<GB, 256, 0, stream>>>(bufA, wc1, dinv, bufB, NN, dflag);
    k_agg<128, true, false><<<NN / 4, 256, 0, stream>>>(bufB, colS, offs, cnt, dinv, bufA, nullptr, dflag, NN);
    // layer 2 (pre-ReLU kept in bufA for corr_2)
    k_gemm<128, 128, false, 0><<<GB, 256, 0, stream>>>(bufA, wc2, dinv, bufB, NN, dflag);
    k_agg<128, false, false><<<NN / 4, 256, 0, stream>>>(bufB, colS, offs, cnt, dinv, bufA, nullptr, dflag, NN);

    // corr_2 on bufA (bf16, D=128)
    hipMemsetAsync(colsum, 0, HD * 4, stream);
    k_colsum<128><<<64, 256, 0, stream>>>(bufA, colsum, NN);
    k_cov2<128><<<NBC, 256, 0, stream>>>(bufA, colsum, part, NN, NBC);
    k_covred<128><<<(HD * HD + 255) / 256, 256, 0, stream>>>(part, covs, NBC);
    k_fin<128><<<1, 256, 0, stream>>>(covs, d_out, (long long)NN * CD, dflag);

    // layer 3: relu(bufA) @ W3 -> bufB ; aggregate -> d_out (+ bf16 mirror in bufA)
    k_gemm<128, 64, true, 0><<<GB, 256, 0, stream>>>(bufA, wc3, dinv, bufB, NN, dflag);
    k_agg<64, false, true><<<NN / 4, 256, 0, stream>>>(bufB, colS, offs, cnt, dinv, bufA, d_out, dflag, NN);

    // corr on final output (bf16 mirror in bufA, D=64)
    hipMemsetAsync(colsum, 0, HD * 4, stream);
    k_colsum<64><<<64, 256, 0, stream>>>(bufA, colsum, NN);
    k_cov2<64><<<NBC, 256, 0, stream>>>(bufA, colsum, part, NN, NBC);
    k_covred<64><<<(CD * CD + 255) / 256, 256, 0, stream>>>(part, covs, NBC);
    k_fin<64><<<1, 256, 0, stream>>>(covs, d_out, (long long)NN * CD + 1, dflag);
}